// Round 1
// baseline (2631.288 us; speedup 1.0000x reference)
//
#include <hip/hip_runtime.h>
#include <math.h>

#define H 256

// ---------------- CSR build ----------------

__global__ void count_deg(const int* __restrict__ dst, int* __restrict__ deg, int E) {
    int e = blockIdx.x * blockDim.x + threadIdx.x;
    if (e < E) atomicAdd(&deg[dst[e]], 1);
}

// single-block exclusive scan (wave-shuffle based), n up to ~100k
__global__ void scan_exclusive(const int* __restrict__ deg, int* __restrict__ row, int n) {
    __shared__ int wsum[16];
    __shared__ int sh_carry;
    int tid = threadIdx.x;            // 1024 threads
    int lane = tid & 63, wid = tid >> 6;
    if (tid == 0) sh_carry = 0;
    __syncthreads();
    for (int base = 0; base < n; base += 1024) {
        int i = base + tid;
        int v = (i < n) ? deg[i] : 0;
        int x = v;
        #pragma unroll
        for (int off = 1; off < 64; off <<= 1) {
            int t = __shfl_up(x, off, 64);
            if (lane >= off) x += t;
        }
        if (lane == 63) wsum[wid] = x;
        __syncthreads();                    // A: wsum ready; also orders sh_carry from prev iter
        int carry = sh_carry;
        int wexc = 0;
        for (int w = 0; w < wid; ++w) wexc += wsum[w];
        int incl = carry + wexc + x;
        if (i < n) row[i + 1] = incl;
        __syncthreads();                    // B: all reads of wsum/sh_carry done
        if (tid == 1023) sh_carry = incl;   // chunk-inclusive total
    }
    __syncthreads();
    if (tid == 0) row[0] = 0;
}

__global__ void fill_csr(const int* __restrict__ src, const int* __restrict__ dst,
                         const int* __restrict__ row, int* __restrict__ cursor,
                         int* __restrict__ srcl, int E) {
    int e = blockIdx.x * blockDim.x + threadIdx.x;
    if (e < E) {
        int d = dst[e];
        int p = atomicAdd(&cursor[d], 1);
        srcl[row[d] + p] = src[e];
    }
}

// ---------------- aggregation: agg[n] = sum_{e: dst=n} x[src[e]] ----------------

template<int F>
__global__ void aggregate(const float* __restrict__ xin, const int* __restrict__ row,
                          const int* __restrict__ srcl, float* __restrict__ agg, int N) {
    int n = blockIdx.x;
    int f = threadIdx.x;   // blockDim == F
    int s0 = row[n], s1 = row[n + 1];
    float acc = 0.f;
    for (int e = s0; e < s1; ++e) {
        int s = srcl[e];
        acc += xin[(long)s * F + f];
    }
    agg[(long)n * F + f] = acc;
}

// ---------------- fused MLP (2 GEMMs) + LayerNorm + ReLU ----------------
// block: 256 threads (one per output column), T-node tile

template<int F_IN, int T>
__global__ void mlp_ln(const float* __restrict__ hin, const float* __restrict__ agg,
                       const float* __restrict__ w1, const float* __restrict__ b1,
                       const float* __restrict__ w2, const float* __restrict__ b2,
                       const float* __restrict__ lng, const float* __restrict__ lnb,
                       float* __restrict__ hout, int N) {
    __shared__ float hrow[T * F_IN];
    __shared__ float hid[T * H];
    __shared__ float up[T * (H + 1)];
    __shared__ float mu_s[T], rs_s[T];
    int tid = threadIdx.x;       // 256
    int n0 = blockIdx.x * T;
    // stage h = hin + agg for the tile
    for (int idx = tid; idx < T * F_IN; idx += 256) {
        int i = idx / F_IN, k = idx - i * F_IN;
        long g = (long)(n0 + i) * F_IN + k;
        hrow[idx] = (n0 + i < N) ? (hin[g] + agg[g]) : 0.f;
    }
    __syncthreads();
    int j = tid;
    // GEMM1 + ReLU
    {
        float acc[T];
        #pragma unroll
        for (int i = 0; i < T; ++i) acc[i] = b1[j];
        #pragma unroll 2
        for (int k = 0; k < F_IN; ++k) {
            float w = w1[(long)k * H + j];
            #pragma unroll
            for (int i = 0; i < T; ++i) acc[i] = fmaf(hrow[i * F_IN + k], w, acc[i]);
        }
        #pragma unroll
        for (int i = 0; i < T; ++i) hid[i * H + j] = fmaxf(acc[i], 0.f);
    }
    __syncthreads();
    // GEMM2
    {
        float acc[T];
        #pragma unroll
        for (int i = 0; i < T; ++i) acc[i] = b2[j];
        #pragma unroll 2
        for (int k = 0; k < H; ++k) {
            float w = w2[(long)k * H + j];
            #pragma unroll
            for (int i = 0; i < T; ++i) acc[i] = fmaf(hid[i * H + k], w, acc[i]);
        }
        #pragma unroll
        for (int i = 0; i < T; ++i) up[i * (H + 1) + j] = acc[i];
    }
    __syncthreads();
    // LayerNorm stats (thread-per-node)
    if (tid < T) {
        int i = tid;
        float s = 0.f, s2 = 0.f;
        for (int k = 0; k < H; ++k) {
            float v = up[i * (H + 1) + k];
            s += v; s2 += v * v;
        }
        float mu = s * (1.0f / H);
        float var = s2 * (1.0f / H) - mu * mu;
        mu_s[i] = mu;
        rs_s[i] = rsqrtf(var + 1e-5f);
    }
    __syncthreads();
    float g = lng[j], bb = lnb[j];
    for (int i = 0; i < T; ++i) {
        if (n0 + i < N) {
            float v = (up[i * (H + 1) + j] - mu_s[i]) * rs_s[i] * g + bb;
            hout[(long)(n0 + i) * H + j] = fmaxf(v, 0.f);
        }
    }
}

// ---------------- gate MLP: gate = relu(h@gw1+gb1) @ gw2 + gb2 ----------------

template<int T>
__global__ void gate_kernel(const float* __restrict__ h, const float* __restrict__ gw1,
                            const float* __restrict__ gb1, const float* __restrict__ gw2,
                            const float* __restrict__ gb2, float* __restrict__ gate, int N) {
    __shared__ float hrow[T * H];
    __shared__ float contrib[T * 129];
    int tid = threadIdx.x;   // 128
    int n0 = blockIdx.x * T;
    for (int idx = tid; idx < T * H; idx += 128) {
        int i = idx / H, k = idx - i * H;
        hrow[idx] = (n0 + i < N) ? h[(long)(n0 + i) * H + k] : 0.f;
    }
    __syncthreads();
    int p = tid;
    float acc[T];
    #pragma unroll
    for (int i = 0; i < T; ++i) acc[i] = gb1[p];
    #pragma unroll 2
    for (int k = 0; k < H; ++k) {
        float w = gw1[(long)k * 128 + p];
        #pragma unroll
        for (int i = 0; i < T; ++i) acc[i] = fmaf(hrow[i * H + k], w, acc[i]);
    }
    float w2v = gw2[p];
    #pragma unroll
    for (int i = 0; i < T; ++i) contrib[i * 129 + p] = fmaxf(acc[i], 0.f) * w2v;
    __syncthreads();
    if (tid < T) {
        int i = tid;
        float s = 0.f;
        for (int k = 0; k < 128; ++k) s += contrib[i * 129 + k];
        if (n0 + i < N) gate[n0 + i] = s + gb2[0];
    }
}

// ---------------- graph ranges (batch is sorted) ----------------

__global__ void boundaries(const int* __restrict__ batch, int* __restrict__ gstart,
                           int* __restrict__ gend, int N) {
    int i = blockIdx.x * blockDim.x + threadIdx.x;
    if (i >= N) return;
    int b = batch[i];
    if (i == 0 || batch[i - 1] != b) gstart[b] = i;
    if (i == N - 1 || batch[i + 1] != b) gend[b] = i + 1;
}

// ---------------- per-graph softmax pooling + classifier ----------------

__global__ void pool_cls(const float* __restrict__ h, const float* __restrict__ gate,
                         const int* __restrict__ gstart, const int* __restrict__ gend,
                         float* __restrict__ ebuf,
                         const float* __restrict__ cw1, const float* __restrict__ cb1,
                         const float* __restrict__ cw2, const float* __restrict__ cb2,
                         float* __restrict__ out) {
    __shared__ float red[256];
    __shared__ float pooled[256];
    __shared__ float c2[128 * 2];
    int g = blockIdx.x;
    int tid = threadIdx.x;   // 256
    int s = gstart[g], e = gend[g];
    // max
    float lmax = -INFINITY;
    for (int n = s + tid; n < e; n += 256) lmax = fmaxf(lmax, gate[n]);
    red[tid] = lmax;
    __syncthreads();
    for (int off = 128; off > 0; off >>= 1) {
        if (tid < off) red[tid] = fmaxf(red[tid], red[tid + off]);
        __syncthreads();
    }
    float gmax = red[0];
    __syncthreads();
    // denom + store exp
    float lsum = 0.f;
    for (int n = s + tid; n < e; n += 256) {
        float ev = expf(gate[n] - gmax);
        ebuf[n] = ev;
        lsum += ev;
    }
    red[tid] = lsum;
    __syncthreads();
    for (int off = 128; off > 0; off >>= 1) {
        if (tid < off) red[tid] += red[tid + off];
        __syncthreads();
    }
    float den = red[0];
    // weighted pool (thread-per-feature)
    int j = tid;
    float acc = 0.f;
    for (int n = s; n < e; ++n) acc += h[(long)n * H + j] * ebuf[n];
    pooled[j] = (e > s) ? acc / den : 0.f;
    __syncthreads();
    // classifier
    if (tid < 128) {
        int p = tid;
        float a = cb1[p];
        #pragma unroll 2
        for (int k = 0; k < H; ++k) a = fmaf(pooled[k], cw1[(long)k * 128 + p], a);
        a = fmaxf(a, 0.f);
        c2[p * 2 + 0] = a * cw2[p * 2 + 0];
        c2[p * 2 + 1] = a * cw2[p * 2 + 1];
    }
    __syncthreads();
    if (tid < 2) {
        float sres = cb2[tid];
        for (int p = 0; p < 128; ++p) sres += c2[p * 2 + tid];
        out[g * 2 + tid] = sres;
    }
}

// ---------------- launch ----------------

extern "C" void kernel_launch(void* const* d_in, const int* in_sizes, int n_in,
                              void* d_out, int out_size, void* d_ws, size_t ws_size,
                              hipStream_t stream) {
    const float* x     = (const float*)d_in[0];
    const int*   ei    = (const int*)d_in[1];
    const int*   batch = (const int*)d_in[2];
    const float* w1_0  = (const float*)d_in[4];
    const float* b1_0  = (const float*)d_in[5];
    const float* w2_0  = (const float*)d_in[6];
    const float* b2_0  = (const float*)d_in[7];
    const float* lng0  = (const float*)d_in[8];
    const float* lnb0  = (const float*)d_in[9];
    const float* w1_1  = (const float*)d_in[10];
    const float* b1_1  = (const float*)d_in[11];
    const float* w2_1  = (const float*)d_in[12];
    const float* b2_1  = (const float*)d_in[13];
    const float* lng1  = (const float*)d_in[14];
    const float* lnb1  = (const float*)d_in[15];
    const float* gw1   = (const float*)d_in[16];
    const float* gb1   = (const float*)d_in[17];
    const float* gw2   = (const float*)d_in[18];
    const float* gb2   = (const float*)d_in[19];
    const float* cw1   = (const float*)d_in[20];
    const float* cb1   = (const float*)d_in[21];
    const float* cw2   = (const float*)d_in[22];
    const float* cb2   = (const float*)d_in[23];

    int N = in_sizes[2];
    int E = in_sizes[1] / 2;
    int G = out_size / 2;
    const int* src = ei;
    const int* dst = ei + E;

    char* p = (char*)d_ws;
    auto alloc = [&](size_t bytes) {
        char* r = p;
        p += (bytes + 255) & ~(size_t)255;
        return r;
    };
    int*   row    = (int*)alloc((size_t)(N + 1) * 4);
    int*   cursor = (int*)alloc((size_t)N * 4);
    int*   srcl   = (int*)alloc((size_t)E * 4);
    float* gate   = (float*)alloc((size_t)N * 4);
    float* ebuf   = (float*)alloc((size_t)N * 4);
    int*   gstart = (int*)alloc((size_t)G * 4);
    int*   gend   = (int*)alloc((size_t)G * 4);
    float* B1     = (float*)alloc((size_t)N * H * 4);
    float* B2     = (float*)alloc((size_t)N * H * 4);

    // CSR build (shared by both layers)
    hipMemsetAsync(cursor, 0, (size_t)N * 4, stream);
    count_deg<<<(E + 255) / 256, 256, 0, stream>>>(dst, cursor, E);
    scan_exclusive<<<1, 1024, 0, stream>>>(cursor, row, N);
    hipMemsetAsync(cursor, 0, (size_t)N * 4, stream);
    fill_csr<<<(E + 255) / 256, 256, 0, stream>>>(src, dst, row, cursor, srcl, E);

    // layer 0
    aggregate<128><<<N, 128, 0, stream>>>(x, row, srcl, B2, N);
    mlp_ln<128, 16><<<(N + 15) / 16, 256, 0, stream>>>(x, B2, w1_0, b1_0, w2_0, b2_0,
                                                       lng0, lnb0, B1, N);
    // layer 1 (in-place on B1: blocks touch disjoint tile rows, reads precede writes)
    aggregate<256><<<N, 256, 0, stream>>>(B1, row, srcl, B2, N);
    mlp_ln<256, 16><<<(N + 15) / 16, 256, 0, stream>>>(B1, B2, w1_1, b1_1, w2_1, b2_1,
                                                       lng1, lnb1, B1, N);
    // gate
    gate_kernel<16><<<(N + 15) / 16, 128, 0, stream>>>(B1, gw1, gb1, gw2, gb2, gate, N);
    // pooling + classifier
    hipMemsetAsync(gstart, 0, (size_t)G * 4, stream);
    hipMemsetAsync(gend, 0, (size_t)G * 4, stream);
    boundaries<<<(N + 255) / 256, 256, 0, stream>>>(batch, gstart, gend, N);
    pool_cls<<<G, 256, 0, stream>>>(B1, gate, gstart, gend, ebuf,
                                    cw1, cb1, cw2, cb2, (float*)d_out);
}

// Round 2
// 1332.590 us; speedup vs baseline: 1.9746x; 1.9746x over previous
//
#include <hip/hip_runtime.h>
#include <math.h>

#define H 256

typedef short short8 __attribute__((ext_vector_type(8)));
typedef float f32x4 __attribute__((ext_vector_type(4)));

__device__ inline ushort f2bf(float f) {
    union { float f; unsigned u; } v; v.f = f;
    unsigned r = v.u + 0x7fff + ((v.u >> 16) & 1);
    return (ushort)(r >> 16);
}
__device__ inline float bf2f(unsigned h) {
    union { unsigned u; float f; } v; v.u = h << 16; return v.f;
}

// ---------------- CSR build ----------------

__global__ void count_deg(const int* __restrict__ dst, int* __restrict__ deg, int E) {
    int e = blockIdx.x * blockDim.x + threadIdx.x;
    if (e < E) atomicAdd(&deg[dst[e]], 1);
}

__global__ void scan_exclusive(const int* __restrict__ deg, int* __restrict__ row, int n) {
    __shared__ int wsum[16];
    __shared__ int sh_carry;
    int tid = threadIdx.x;            // 1024 threads
    int lane = tid & 63, wid = tid >> 6;
    if (tid == 0) sh_carry = 0;
    __syncthreads();
    for (int base = 0; base < n; base += 1024) {
        int i = base + tid;
        int v = (i < n) ? deg[i] : 0;
        int x = v;
        #pragma unroll
        for (int off = 1; off < 64; off <<= 1) {
            int t = __shfl_up(x, off, 64);
            if (lane >= off) x += t;
        }
        if (lane == 63) wsum[wid] = x;
        __syncthreads();
        int carry = sh_carry;
        int wexc = 0;
        for (int w = 0; w < wid; ++w) wexc += wsum[w];
        int incl = carry + wexc + x;
        if (i < n) row[i + 1] = incl;
        __syncthreads();
        if (tid == 1023) sh_carry = incl;
    }
    __syncthreads();
    if (tid == 0) row[0] = 0;
}

__global__ void fill_csr(const int* __restrict__ src, const int* __restrict__ dst,
                         const int* __restrict__ row, int* __restrict__ cursor,
                         int* __restrict__ srcl, int E) {
    int e = blockIdx.x * blockDim.x + threadIdx.x;
    if (e < E) {
        int d = dst[e];
        int p = atomicAdd(&cursor[d], 1);
        srcl[row[d] + p] = src[e];
    }
}

// ---------------- weight prep: fp32 -> bf16 transposed ----------------
// w1t[n][k] = w[k][n]

__global__ void prep_weights(const float* __restrict__ w10, const float* __restrict__ w20,
                             const float* __restrict__ w11, const float* __restrict__ w21,
                             const float* __restrict__ gw1,
                             ushort* __restrict__ w1t0, ushort* __restrict__ w2t0,
                             ushort* __restrict__ w1t1, ushort* __restrict__ w2t1,
                             ushort* __restrict__ gw1t) {
    int i = blockIdx.x * 256 + threadIdx.x;
    if (i < 32768) {                       // w10: 128x256
        int k = i >> 8, n = i & 255;
        w1t0[n * 128 + k] = f2bf(w10[i]);
    } else if (i < 32768 + 65536) {        // w20: 256x256
        int j = i - 32768; int k = j >> 8, n = j & 255;
        w2t0[n * 256 + k] = f2bf(w20[j]);
    } else if (i < 32768 + 131072) {       // w11: 256x256
        int j = i - (32768 + 65536); int k = j >> 8, n = j & 255;
        w1t1[n * 256 + k] = f2bf(w11[j]);
    } else if (i < 32768 + 196608) {       // w21: 256x256
        int j = i - (32768 + 131072); int k = j >> 8, n = j & 255;
        w2t1[n * 256 + k] = f2bf(w21[j]);
    } else if (i < 32768 + 196608 + 32768) { // gw1: 256x128
        int j = i - (32768 + 196608); int k = j >> 7, n = j & 127;
        gw1t[n * 256 + k] = f2bf(gw1[j]);
    }
}

// ---------------- aggregation ----------------
// layer0: x fp32 [N][128] -> hsum0 bf16 = x[n] + sum x[src]

__global__ void aggregate0(const float* __restrict__ x, const int* __restrict__ row,
                           const int* __restrict__ srcl, ushort* __restrict__ out, int N) {
    int n = blockIdx.x;
    int f = threadIdx.x;   // 128
    int s0 = row[n], s1 = row[n + 1];
    float acc = x[(size_t)n * 128 + f];
    for (int e = s0; e < s1; ++e) acc += x[(size_t)srcl[e] * 128 + f];
    out[(size_t)n * 128 + f] = f2bf(acc);
}

// layer1: h bf16 [N][256] -> hsum1 bf16

__global__ void aggregate1(const ushort* __restrict__ h, const int* __restrict__ row,
                           const int* __restrict__ srcl, ushort* __restrict__ out, int N) {
    int n = blockIdx.x;
    int f = threadIdx.x;   // 128 threads x 2 features
    const unsigned* h32 = (const unsigned*)h;
    int s0 = row[n], s1 = row[n + 1];
    unsigned v = h32[(size_t)n * 128 + f];
    float a0 = bf2f(v & 0xffffu), a1 = bf2f(v >> 16);
    for (int e = s0; e < s1; ++e) {
        unsigned u = h32[(size_t)srcl[e] * 128 + f];
        a0 += bf2f(u & 0xffffu); a1 += bf2f(u >> 16);
    }
    ((unsigned*)out)[(size_t)n * 128 + f] = (unsigned)f2bf(a0) | ((unsigned)f2bf(a1) << 16);
}

// ---------------- fused MFMA MLP + LN (+ gate) ----------------
// One wave per 16 rows. A-frags from global (bf16 row-major), B-frags from
// transposed bf16 weights (L2-resident). GEMM1 -> relu -> LDS (XOR swizzle)
// -> GEMM2 -> in-register LayerNorm -> bf16 h_out (+ fused gate MLP).

template<int K1, bool DO_GATE>
__global__ void __launch_bounds__(256) mlp_mfma(
        const ushort* __restrict__ hsum, const ushort* __restrict__ w1t,
        const float* __restrict__ b1, const ushort* __restrict__ w2t,
        const float* __restrict__ b2, const float* __restrict__ lng,
        const float* __restrict__ lnb, ushort* __restrict__ hout,
        const ushort* __restrict__ gw1t, const float* __restrict__ gb1,
        const float* __restrict__ gw2, const float* __restrict__ gb2,
        float* __restrict__ gate, int N) {
    __shared__ ushort lds[4][16 * 256];
    int tid = threadIdx.x;
    int wib = tid >> 6;
    int lane = tid & 63;
    int ll = lane & 15, kg = lane >> 4;
    int n0 = (blockIdx.x * 4 + wib) * 16;
    if (n0 >= N) return;                    // no barriers in this kernel
    int arow = n0 + ll; if (arow >= N) arow = N - 1;
    ushort* myl = lds[wib];

    // ---- GEMM1: hid = relu(hsum @ W1 + b1) ----
    f32x4 acc[16] = {};
    const short8* a_base = (const short8*)(hsum + (size_t)arow * K1);
    #pragma unroll
    for (int kc = 0; kc < K1 / 32; ++kc) {
        short8 a = a_base[kc * 4 + kg];
        #pragma unroll
        for (int c = 0; c < 16; ++c) {
            const short8* bp = (const short8*)(w1t + (size_t)(c * 16 + ll) * K1);
            short8 b = bp[kc * 4 + kg];
            acc[c] = __builtin_amdgcn_mfma_f32_16x16x32_bf16(a, b, acc[c], 0, 0, 0);
        }
    }
    #pragma unroll
    for (int c = 0; c < 16; ++c) {
        float bc = b1[c * 16 + ll];
        int col = c * 16 + ll;
        int bir = col * 2;
        #pragma unroll
        for (int r = 0; r < 4; ++r) {
            int rowi = kg * 4 + r;
            float v = fmaxf(acc[c][r] + bc, 0.f);
            int sb = rowi * 512 + ((((bir >> 4) ^ (rowi & 7))) << 4) + (bir & 15);
            myl[sb >> 1] = f2bf(v);
        }
    }

    // ---- GEMM2: up = hid @ W2 + b2 ----
    f32x4 acc2[16] = {};
    #pragma unroll
    for (int kc = 0; kc < 8; ++kc) {
        int bir = kc * 64 + kg * 16;
        int sb = ll * 512 + ((((bir >> 4) ^ (ll & 7))) << 4);
        short8 a = *(const short8*)(myl + (sb >> 1));
        #pragma unroll
        for (int c = 0; c < 16; ++c) {
            const short8* bp = (const short8*)(w2t + (size_t)(c * 16 + ll) * 256);
            short8 b = bp[kc * 4 + kg];
            acc2[c] = __builtin_amdgcn_mfma_f32_16x16x32_bf16(a, b, acc2[c], 0, 0, 0);
        }
    }

    // ---- LayerNorm (in-register, 16-lane shuffle reduce) ----
    float s[4] = {0, 0, 0, 0}, s2[4] = {0, 0, 0, 0};
    #pragma unroll
    for (int c = 0; c < 16; ++c) {
        float bc = b2[c * 16 + ll];
        #pragma unroll
        for (int r = 0; r < 4; ++r) {
            float v = acc2[c][r] + bc;
            acc2[c][r] = v;
            s[r] += v; s2[r] += v * v;
        }
    }
    #pragma unroll
    for (int r = 0; r < 4; ++r) {
        float a = s[r], q = s2[r];
        #pragma unroll
        for (int m = 1; m < 16; m <<= 1) {
            a += __shfl_xor(a, m, 64);
            q += __shfl_xor(q, m, 64);
        }
        float mu = a * (1.f / 256.f);
        float var = q * (1.f / 256.f) - mu * mu;
        s[r] = mu;
        s2[r] = rsqrtf(var + 1e-5f);
    }
    #pragma unroll
    for (int c = 0; c < 16; ++c) {
        int col = c * 16 + ll;
        float gc = lng[col], bc = lnb[col];
        int bir = col * 2;
        #pragma unroll
        for (int r = 0; r < 4; ++r) {
            float v = fmaxf((acc2[c][r] - s[r]) * s2[r] * gc + bc, 0.f);
            ushort hb = f2bf(v);
            int n = n0 + kg * 4 + r;
            if (n < N) hout[(size_t)n * 256 + col] = hb;
            if (DO_GATE) {
                int rowi = kg * 4 + r;
                int sb = rowi * 512 + ((((bir >> 4) ^ (rowi & 7))) << 4) + (bir & 15);
                myl[sb >> 1] = hb;
            }
        }
    }

    // ---- fused gate MLP: gate = relu(h @ gw1 + gb1) @ gw2 + gb2 ----
    if (DO_GATE) {
        f32x4 ag[8] = {};
        #pragma unroll
        for (int kc = 0; kc < 8; ++kc) {
            int bir = kc * 64 + kg * 16;
            int sb = ll * 512 + ((((bir >> 4) ^ (ll & 7))) << 4);
            short8 a = *(const short8*)(myl + (sb >> 1));
            #pragma unroll
            for (int c = 0; c < 8; ++c) {
                const short8* bp = (const short8*)(gw1t + (size_t)(c * 16 + ll) * 256);
                short8 b = bp[kc * 4 + kg];
                ag[c] = __builtin_amdgcn_mfma_f32_16x16x32_bf16(a, b, ag[c], 0, 0, 0);
            }
        }
        float gs[4] = {0, 0, 0, 0};
        #pragma unroll
        for (int c = 0; c < 8; ++c) {
            float bc = gb1[c * 16 + ll];
            float wv = gw2[c * 16 + ll];
            #pragma unroll
            for (int r = 0; r < 4; ++r)
                gs[r] += fmaxf(ag[c][r] + bc, 0.f) * wv;
        }
        float gb = gb2[0];
        #pragma unroll
        for (int r = 0; r < 4; ++r) {
            float a = gs[r];
            #pragma unroll
            for (int m = 1; m < 16; m <<= 1) a += __shfl_xor(a, m, 64);
            int n = n0 + kg * 4 + r;
            if (ll == 0 && n < N) gate[n] = a + gb;
        }
    }
}

// ---------------- graph ranges ----------------

__global__ void boundaries(const int* __restrict__ batch, int* __restrict__ gstart,
                           int* __restrict__ gend, int N) {
    int i = blockIdx.x * blockDim.x + threadIdx.x;
    if (i >= N) return;
    int b = batch[i];
    if (i == 0 || batch[i - 1] != b) gstart[b] = i;
    if (i == N - 1 || batch[i + 1] != b) gend[b] = i + 1;
}

// ---------------- per-graph softmax pooling + classifier ----------------

__global__ void pool_cls(const ushort* __restrict__ h, const float* __restrict__ gate,
                         const int* __restrict__ gstart, const int* __restrict__ gend,
                         float* __restrict__ ebuf,
                         const float* __restrict__ cw1, const float* __restrict__ cb1,
                         const float* __restrict__ cw2, const float* __restrict__ cb2,
                         float* __restrict__ out) {
    __shared__ float red[256];
    __shared__ float pooled[256];
    __shared__ float c2[128 * 2];
    int g = blockIdx.x;
    int tid = threadIdx.x;   // 256
    int s = gstart[g], e = gend[g];
    float lmax = -INFINITY;
    for (int n = s + tid; n < e; n += 256) lmax = fmaxf(lmax, gate[n]);
    red[tid] = lmax;
    __syncthreads();
    for (int off = 128; off > 0; off >>= 1) {
        if (tid < off) red[tid] = fmaxf(red[tid], red[tid + off]);
        __syncthreads();
    }
    float gmax = red[0];
    __syncthreads();
    float lsum = 0.f;
    for (int n = s + tid; n < e; n += 256) {
        float ev = expf(gate[n] - gmax);
        ebuf[n] = ev;
        lsum += ev;
    }
    red[tid] = lsum;
    __syncthreads();
    for (int off = 128; off > 0; off >>= 1) {
        if (tid < off) red[tid] += red[tid + off];
        __syncthreads();
    }
    float den = red[0];
    int j = tid;
    float acc = 0.f;
    for (int n = s; n < e; ++n) acc += bf2f(h[(size_t)n * H + j]) * ebuf[n];
    pooled[j] = (e > s) ? acc / den : 0.f;
    __syncthreads();
    if (tid < 128) {
        int p = tid;
        float a = cb1[p];
        #pragma unroll 2
        for (int k = 0; k < H; ++k) a = fmaf(pooled[k], cw1[(size_t)k * 128 + p], a);
        a = fmaxf(a, 0.f);
        c2[p * 2 + 0] = a * cw2[p * 2 + 0];
        c2[p * 2 + 1] = a * cw2[p * 2 + 1];
    }
    __syncthreads();
    if (tid < 2) {
        float sres = cb2[tid];
        for (int p = 0; p < 128; ++p) sres += c2[p * 2 + tid];
        out[g * 2 + tid] = sres;
    }
}

// ---------------- launch ----------------

extern "C" void kernel_launch(void* const* d_in, const int* in_sizes, int n_in,
                              void* d_out, int out_size, void* d_ws, size_t ws_size,
                              hipStream_t stream) {
    const float* x     = (const float*)d_in[0];
    const int*   ei    = (const int*)d_in[1];
    const int*   batch = (const int*)d_in[2];
    const float* w1_0  = (const float*)d_in[4];
    const float* b1_0  = (const float*)d_in[5];
    const float* w2_0  = (const float*)d_in[6];
    const float* b2_0  = (const float*)d_in[7];
    const float* lng0  = (const float*)d_in[8];
    const float* lnb0  = (const float*)d_in[9];
    const float* w1_1  = (const float*)d_in[10];
    const float* b1_1  = (const float*)d_in[11];
    const float* w2_1  = (const float*)d_in[12];
    const float* b2_1  = (const float*)d_in[13];
    const float* lng1  = (const float*)d_in[14];
    const float* lnb1  = (const float*)d_in[15];
    const float* gw1   = (const float*)d_in[16];
    const float* gb1   = (const float*)d_in[17];
    const float* gw2   = (const float*)d_in[18];
    const float* gb2   = (const float*)d_in[19];
    const float* cw1   = (const float*)d_in[20];
    const float* cb1   = (const float*)d_in[21];
    const float* cw2   = (const float*)d_in[22];
    const float* cb2   = (const float*)d_in[23];

    int N = in_sizes[2];
    int E = in_sizes[1] / 2;
    int G = out_size / 2;
    const int* src = ei;
    const int* dst = ei + E;

    char* p = (char*)d_ws;
    auto alloc = [&](size_t bytes) {
        char* r = p;
        p += (bytes + 255) & ~(size_t)255;
        return r;
    };
    int*    row    = (int*)alloc((size_t)(N + 1) * 4);
    int*    cursor = (int*)alloc((size_t)N * 4);
    int*    srcl   = (int*)alloc((size_t)E * 4);
    float*  gate   = (float*)alloc((size_t)N * 4);
    float*  ebuf   = (float*)alloc((size_t)N * 4);
    int*    gstart = (int*)alloc((size_t)G * 4);
    int*    gend   = (int*)alloc((size_t)G * 4);
    ushort* hsum0  = (ushort*)alloc((size_t)N * 128 * 2);
    ushort* h1     = (ushort*)alloc((size_t)N * 256 * 2);
    ushort* hsum1  = (ushort*)alloc((size_t)N * 256 * 2);
    ushort* h2     = (ushort*)alloc((size_t)N * 256 * 2);
    ushort* w1t0   = (ushort*)alloc(128 * 256 * 2);
    ushort* w2t0   = (ushort*)alloc(256 * 256 * 2);
    ushort* w1t1   = (ushort*)alloc(256 * 256 * 2);
    ushort* w2t1   = (ushort*)alloc(256 * 256 * 2);
    ushort* gw1t   = (ushort*)alloc(128 * 256 * 2);

    // weight prep + CSR build
    prep_weights<<<1024, 256, 0, stream>>>(w1_0, w2_0, w1_1, w2_1, gw1,
                                           w1t0, w2t0, w1t1, w2t1, gw1t);
    hipMemsetAsync(cursor, 0, (size_t)N * 4, stream);
    count_deg<<<(E + 255) / 256, 256, 0, stream>>>(dst, cursor, E);
    scan_exclusive<<<1, 1024, 0, stream>>>(cursor, row, N);
    hipMemsetAsync(cursor, 0, (size_t)N * 4, stream);
    fill_csr<<<(E + 255) / 256, 256, 0, stream>>>(src, dst, row, cursor, srcl, E);

    int mlp_blocks = (N + 63) / 64;
    // layer 0
    aggregate0<<<N, 128, 0, stream>>>(x, row, srcl, hsum0, N);
    mlp_mfma<128, false><<<mlp_blocks, 256, 0, stream>>>(
        hsum0, w1t0, b1_0, w2t0, b2_0, lng0, lnb0, h1,
        nullptr, nullptr, nullptr, nullptr, nullptr, N);
    // layer 1 + fused gate
    aggregate1<<<N, 128, 0, stream>>>(h1, row, srcl, hsum1, N);
    mlp_mfma<256, true><<<mlp_blocks, 256, 0, stream>>>(
        hsum1, w1t1, b1_1, w2t1, b2_1, lng1, lnb1, h2,
        gw1t, gb1, gw2, gb2, gate, N);
    // pooling + classifier
    hipMemsetAsync(gstart, 0, (size_t)G * 4, stream);
    hipMemsetAsync(gend, 0, (size_t)G * 4, stream);
    boundaries<<<(N + 255) / 256, 256, 0, stream>>>(batch, gstart, gend, N);
    pool_cls<<<G, 256, 0, stream>>>(h2, gate, gstart, gend, ebuf,
                                    cw1, cb1, cw2, cb2, (float*)d_out);
}

// Round 3
// 1290.327 us; speedup vs baseline: 2.0392x; 1.0328x over previous
//
#include <hip/hip_runtime.h>
#include <math.h>

#define H 256

typedef short short8 __attribute__((ext_vector_type(8)));
typedef float f32x4 __attribute__((ext_vector_type(4)));

__device__ inline ushort f2bf(float f) {
    union { float f; unsigned u; } v; v.f = f;
    unsigned r = v.u + 0x7fff + ((v.u >> 16) & 1);
    return (ushort)(r >> 16);
}
__device__ inline float bf2f(unsigned h) {
    union { unsigned u; float f; } v; v.u = h << 16; return v.f;
}
__device__ inline unsigned pack2(float a, float b) {
    return (unsigned)f2bf(a) | ((unsigned)f2bf(b) << 16);
}

// ---------------- CSR build ----------------

__global__ void count_deg(const int* __restrict__ dst, int* __restrict__ deg, int E) {
    int e = blockIdx.x * blockDim.x + threadIdx.x;
    if (e < E) atomicAdd(&deg[dst[e]], 1);
}

__global__ void scan_exclusive(const int* __restrict__ deg, int* __restrict__ row, int n) {
    __shared__ int wsum[16];
    __shared__ int sh_carry;
    int tid = threadIdx.x;            // 1024 threads
    int lane = tid & 63, wid = tid >> 6;
    if (tid == 0) sh_carry = 0;
    __syncthreads();
    for (int base = 0; base < n; base += 1024) {
        int i = base + tid;
        int v = (i < n) ? deg[i] : 0;
        int x = v;
        #pragma unroll
        for (int off = 1; off < 64; off <<= 1) {
            int t = __shfl_up(x, off, 64);
            if (lane >= off) x += t;
        }
        if (lane == 63) wsum[wid] = x;
        __syncthreads();
        int carry = sh_carry;
        int wexc = 0;
        for (int w = 0; w < wid; ++w) wexc += wsum[w];
        int incl = carry + wexc + x;
        if (i < n) row[i + 1] = incl;
        __syncthreads();
        if (tid == 1023) sh_carry = incl;
    }
    __syncthreads();
    if (tid == 0) row[0] = 0;
}

__global__ void fill_csr(const int* __restrict__ src, const int* __restrict__ dst,
                         const int* __restrict__ row, int* __restrict__ cursor,
                         int* __restrict__ srcl, int E) {
    int e = blockIdx.x * blockDim.x + threadIdx.x;
    if (e < E) {
        int d = dst[e];
        int p = atomicAdd(&cursor[d], 1);
        srcl[row[d] + p] = src[e];
    }
}

// ---------------- weight prep: fp32 -> bf16 transposed ----------------

__global__ void prep_weights(const float* __restrict__ w10, const float* __restrict__ w20,
                             const float* __restrict__ w11, const float* __restrict__ w21,
                             const float* __restrict__ gw1,
                             ushort* __restrict__ w1t0, ushort* __restrict__ w2t0,
                             ushort* __restrict__ w1t1, ushort* __restrict__ w2t1,
                             ushort* __restrict__ gw1t) {
    int i = blockIdx.x * 256 + threadIdx.x;
    if (i < 32768) {                       // w10: 128x256
        int k = i >> 8, n = i & 255;
        w1t0[n * 128 + k] = f2bf(w10[i]);
    } else if (i < 32768 + 65536) {        // w20: 256x256
        int j = i - 32768; int k = j >> 8, n = j & 255;
        w2t0[n * 256 + k] = f2bf(w20[j]);
    } else if (i < 32768 + 131072) {       // w11: 256x256
        int j = i - (32768 + 65536); int k = j >> 8, n = j & 255;
        w1t1[n * 256 + k] = f2bf(w11[j]);
    } else if (i < 32768 + 196608) {       // w21: 256x256
        int j = i - (32768 + 131072); int k = j >> 8, n = j & 255;
        w2t1[n * 256 + k] = f2bf(w21[j]);
    } else if (i < 32768 + 196608 + 32768) { // gw1: 256x128
        int j = i - (32768 + 196608); int k = j >> 7, n = j & 127;
        gw1t[n * 256 + k] = f2bf(gw1[j]);
    }
}

// ---------------- x -> bf16 ----------------

__global__ void xcast(const float* __restrict__ x, unsigned long long* __restrict__ xb, int n4) {
    int i = blockIdx.x * 256 + threadIdx.x;
    if (i < n4) {
        f32x4 v = ((const f32x4*)x)[i];
        unsigned lo = pack2(v[0], v[1]);
        unsigned hi = pack2(v[2], v[3]);
        xb[i] = (unsigned long long)lo | ((unsigned long long)hi << 32);
    }
}

// ---------------- aggregation (wave per node) ----------------
// layer0: x bf16 [N][128]: lane reads 1 u32 (2 feats)

__global__ void aggregate0(const unsigned* __restrict__ xb, const int* __restrict__ row,
                           const int* __restrict__ srcl, unsigned* __restrict__ out, int N) {
    int n = blockIdx.x * 4 + (threadIdx.x >> 6);
    int f = threadIdx.x & 63;
    if (n >= N) return;
    unsigned v = xb[(size_t)n * 64 + f];
    float a0 = bf2f(v & 0xffffu), a1 = bf2f(v >> 16);
    int s0 = row[n], s1 = row[n + 1];
    for (int e = s0; e < s1; ++e) {
        unsigned u = xb[(size_t)srcl[e] * 64 + f];
        a0 += bf2f(u & 0xffffu); a1 += bf2f(u >> 16);
    }
    out[(size_t)n * 64 + f] = pack2(a0, a1);
}

// layer1: h bf16 [N][256]: lane reads 8B (4 feats)

__global__ void aggregate1(const unsigned long long* __restrict__ h, const int* __restrict__ row,
                           const int* __restrict__ srcl, unsigned long long* __restrict__ out, int N) {
    int n = blockIdx.x * 4 + (threadIdx.x >> 6);
    int f = threadIdx.x & 63;
    if (n >= N) return;
    unsigned long long v = h[(size_t)n * 64 + f];
    float a0 = bf2f((unsigned)(v & 0xffff)), a1 = bf2f((unsigned)((v >> 16) & 0xffff));
    float a2 = bf2f((unsigned)((v >> 32) & 0xffff)), a3 = bf2f((unsigned)(v >> 48));
    int s0 = row[n], s1 = row[n + 1];
    for (int e = s0; e < s1; ++e) {
        unsigned long long u = h[(size_t)srcl[e] * 64 + f];
        a0 += bf2f((unsigned)(u & 0xffff));
        a1 += bf2f((unsigned)((u >> 16) & 0xffff));
        a2 += bf2f((unsigned)((u >> 32) & 0xffff));
        a3 += bf2f((unsigned)(u >> 48));
    }
    unsigned lo = pack2(a0, a1), hi = pack2(a2, a3);
    out[(size_t)n * 64 + f] = (unsigned long long)lo | ((unsigned long long)hi << 32);
}

// ---------------- fused MFMA MLP + LN (+ gate), LDS-free ----------------
// 1 wave per 16 nodes. All GEMMs operand-swapped: C col = node (lane&15),
// C row = feature. In-register shuffle transpose between GEMMs.

__device__ inline short8 build_frag(const unsigned pk[16][2], int kc2, int s1, int hi) {
    // target lane needs k = kc2*32 + kg*8 + 0..7 of its node; sources are
    // lanes s1 (cols +0..3) and s1+16 (cols +4..7) of tile 2*kc2 + (kg>>1).
    unsigned a0 = __shfl(pk[2 * kc2][0], s1, 64);
    unsigned a1 = __shfl(pk[2 * kc2][1], s1, 64);
    unsigned a2 = __shfl(pk[2 * kc2][0], s1 + 16, 64);
    unsigned a3 = __shfl(pk[2 * kc2][1], s1 + 16, 64);
    unsigned b0 = __shfl(pk[2 * kc2 + 1][0], s1, 64);
    unsigned b1 = __shfl(pk[2 * kc2 + 1][1], s1, 64);
    unsigned b2 = __shfl(pk[2 * kc2 + 1][0], s1 + 16, 64);
    unsigned b3 = __shfl(pk[2 * kc2 + 1][1], s1 + 16, 64);
    union { unsigned u[4]; short8 s; } fr;
    fr.u[0] = hi ? b0 : a0;
    fr.u[1] = hi ? b1 : a1;
    fr.u[2] = hi ? b2 : a2;
    fr.u[3] = hi ? b3 : a3;
    return fr.s;
}

template<int K1, bool DO_GATE>
__global__ void __launch_bounds__(64, 3) mlp_mfma(
        const ushort* __restrict__ hsum, const ushort* __restrict__ w1t,
        const float* __restrict__ b1, const ushort* __restrict__ w2t,
        const float* __restrict__ b2, const float* __restrict__ lng,
        const float* __restrict__ lnb, ushort* __restrict__ hout,
        const ushort* __restrict__ gw1t, const float* __restrict__ gb1,
        const float* __restrict__ gw2, const float* __restrict__ gb2,
        float* __restrict__ gate, int N) {
    int lane = threadIdx.x;
    int ll = lane & 15, kg = lane >> 4;
    int n0 = blockIdx.x * 16;
    int nrow = n0 + ll; if (nrow >= N) nrow = N - 1;
    int s1 = ll + (kg & 1) * 32;
    int hi = kg >> 1;

    const short8* hrow = (const short8*)(hsum + (size_t)nrow * K1);

    // ---- GEMM1 (swapped): acc[t] = (W1^T hsum^T) tile t ----
    f32x4 acc[16];
    #pragma unroll
    for (int t = 0; t < 16; ++t) acc[t] = (f32x4){0.f, 0.f, 0.f, 0.f};
    #pragma unroll
    for (int kc = 0; kc < K1 / 32; ++kc) {
        short8 bfrag = hrow[kc * 4 + kg];
        #pragma unroll
        for (int t = 0; t < 16; ++t) {
            short8 afrag = *(const short8*)(w1t + (size_t)(16 * t + ll) * K1 + kc * 32 + kg * 8);
            acc[t] = __builtin_amdgcn_mfma_f32_16x16x32_bf16(afrag, bfrag, acc[t], 0, 0, 0);
        }
    }
    // bias + relu + pack: lane holds hid cols 16t+4kg+{0..3} of node n0+ll
    unsigned pk[16][2];
    #pragma unroll
    for (int t = 0; t < 16; ++t) {
        f32x4 bq = *(const f32x4*)(b1 + 16 * t + 4 * kg);
        float v0 = fmaxf(acc[t][0] + bq[0], 0.f);
        float v1 = fmaxf(acc[t][1] + bq[1], 0.f);
        float v2 = fmaxf(acc[t][2] + bq[2], 0.f);
        float v3 = fmaxf(acc[t][3] + bq[3], 0.f);
        pk[t][0] = pack2(v0, v1);
        pk[t][1] = pack2(v2, v3);
    }

    // ---- GEMM2 (swapped): acc[tj] = (W2^T hid^T) tile tj ----
    #pragma unroll
    for (int t = 0; t < 16; ++t) acc[t] = (f32x4){0.f, 0.f, 0.f, 0.f};
    #pragma unroll
    for (int kc = 0; kc < 8; ++kc) {
        short8 bfrag = build_frag(pk, kc, s1, hi);
        #pragma unroll
        for (int tj = 0; tj < 16; ++tj) {
            short8 afrag = *(const short8*)(w2t + (size_t)(16 * tj + ll) * 256 + kc * 32 + kg * 8);
            acc[tj] = __builtin_amdgcn_mfma_f32_16x16x32_bf16(afrag, bfrag, acc[tj], 0, 0, 0);
        }
    }

    // ---- LayerNorm: lane holds out cols 16tj+4kg+{0..3} of its node ----
    float s = 0.f, s2 = 0.f;
    #pragma unroll
    for (int tj = 0; tj < 16; ++tj) {
        f32x4 bq = *(const f32x4*)(b2 + 16 * tj + 4 * kg);
        #pragma unroll
        for (int r = 0; r < 4; ++r) {
            float v = acc[tj][r] + bq[r];
            acc[tj][r] = v;
            s += v; s2 += v * v;
        }
    }
    s += __shfl_xor(s, 16, 64);  s += __shfl_xor(s, 32, 64);
    s2 += __shfl_xor(s2, 16, 64); s2 += __shfl_xor(s2, 32, 64);
    float mu = s * (1.f / 256.f);
    float var = s2 * (1.f / 256.f) - mu * mu;
    float rs = rsqrtf(var + 1e-5f);

    bool wr = (n0 + ll) < N;
    unsigned long long* orow = (unsigned long long*)(hout + (size_t)(n0 + ll) * 256);
    #pragma unroll
    for (int tj = 0; tj < 16; ++tj) {
        f32x4 gq = *(const f32x4*)(lng + 16 * tj + 4 * kg);
        f32x4 bq = *(const f32x4*)(lnb + 16 * tj + 4 * kg);
        float v0 = fmaxf((acc[tj][0] - mu) * rs * gq[0] + bq[0], 0.f);
        float v1 = fmaxf((acc[tj][1] - mu) * rs * gq[1] + bq[1], 0.f);
        float v2 = fmaxf((acc[tj][2] - mu) * rs * gq[2] + bq[2], 0.f);
        float v3 = fmaxf((acc[tj][3] - mu) * rs * gq[3] + bq[3], 0.f);
        unsigned lo = pack2(v0, v1), hiw = pack2(v2, v3);
        pk[tj][0] = lo; pk[tj][1] = hiw;
        if (wr) orow[tj * 4 + kg] = (unsigned long long)lo | ((unsigned long long)hiw << 32);
    }

    // ---- gate (swapped): ag[t] = (Gw1^T h^T) tile t, t<8 ----
    if (DO_GATE) {
        #pragma unroll
        for (int t = 0; t < 8; ++t) acc[t] = (f32x4){0.f, 0.f, 0.f, 0.f};
        #pragma unroll
        for (int kc = 0; kc < 8; ++kc) {
            short8 bfrag = build_frag(pk, kc, s1, hi);
            #pragma unroll
            for (int t = 0; t < 8; ++t) {
                short8 afrag = *(const short8*)(gw1t + (size_t)(16 * t + ll) * 256 + kc * 32 + kg * 8);
                acc[t] = __builtin_amdgcn_mfma_f32_16x16x32_bf16(afrag, bfrag, acc[t], 0, 0, 0);
            }
        }
        float gs = 0.f;
        #pragma unroll
        for (int t = 0; t < 8; ++t) {
            f32x4 gbq = *(const f32x4*)(gb1 + 16 * t + 4 * kg);
            f32x4 gwq = *(const f32x4*)(gw2 + 16 * t + 4 * kg);
            #pragma unroll
            for (int r = 0; r < 4; ++r)
                gs += fmaxf(acc[t][r] + gbq[r], 0.f) * gwq[r];
        }
        gs += __shfl_xor(gs, 16, 64);
        gs += __shfl_xor(gs, 32, 64);
        if (lane < 16 && wr) gate[n0 + ll] = gs + gb2[0];
    }
}

// ---------------- graph ranges ----------------

__global__ void boundaries(const int* __restrict__ batch, int* __restrict__ gstart,
                           int* __restrict__ gend, int N) {
    int i = blockIdx.x * blockDim.x + threadIdx.x;
    if (i >= N) return;
    int b = batch[i];
    if (i == 0 || batch[i - 1] != b) gstart[b] = i;
    if (i == N - 1 || batch[i + 1] != b) gend[b] = i + 1;
}

// ---------------- per-graph softmax pooling + classifier ----------------

__global__ void pool_cls(const ushort* __restrict__ h, const float* __restrict__ gate,
                         const int* __restrict__ gstart, const int* __restrict__ gend,
                         float* __restrict__ ebuf,
                         const float* __restrict__ cw1, const float* __restrict__ cb1,
                         const float* __restrict__ cw2, const float* __restrict__ cb2,
                         float* __restrict__ out) {
    __shared__ float red[256];
    __shared__ float pooled[256];
    __shared__ float c2[128 * 2];
    int g = blockIdx.x;
    int tid = threadIdx.x;   // 256
    int s = gstart[g], e = gend[g];
    float lmax = -INFINITY;
    for (int n = s + tid; n < e; n += 256) lmax = fmaxf(lmax, gate[n]);
    red[tid] = lmax;
    __syncthreads();
    for (int off = 128; off > 0; off >>= 1) {
        if (tid < off) red[tid] = fmaxf(red[tid], red[tid + off]);
        __syncthreads();
    }
    float gmax = red[0];
    __syncthreads();
    float lsum = 0.f;
    for (int n = s + tid; n < e; n += 256) {
        float ev = expf(gate[n] - gmax);
        ebuf[n] = ev;
        lsum += ev;
    }
    red[tid] = lsum;
    __syncthreads();
    for (int off = 128; off > 0; off >>= 1) {
        if (tid < off) red[tid] += red[tid + off];
        __syncthreads();
    }
    float den = red[0];
    int j = tid;
    float acc = 0.f;
    for (int n = s; n < e; ++n) acc += bf2f(h[(size_t)n * H + j]) * ebuf[n];
    pooled[j] = (e > s) ? acc / den : 0.f;
    __syncthreads();
    if (tid < 128) {
        int p = tid;
        float a = cb1[p];
        #pragma unroll 2
        for (int k = 0; k < H; ++k) a = fmaf(pooled[k], cw1[(size_t)k * 128 + p], a);
        a = fmaxf(a, 0.f);
        c2[p * 2 + 0] = a * cw2[p * 2 + 0];
        c2[p * 2 + 1] = a * cw2[p * 2 + 1];
    }
    __syncthreads();
    if (tid < 2) {
        float sres = cb2[tid];
        for (int p = 0; p < 128; ++p) sres += c2[p * 2 + tid];
        out[g * 2 + tid] = sres;
    }
}

// ---------------- launch ----------------

extern "C" void kernel_launch(void* const* d_in, const int* in_sizes, int n_in,
                              void* d_out, int out_size, void* d_ws, size_t ws_size,
                              hipStream_t stream) {
    const float* x     = (const float*)d_in[0];
    const int*   ei    = (const int*)d_in[1];
    const int*   batch = (const int*)d_in[2];
    const float* w1_0  = (const float*)d_in[4];
    const float* b1_0  = (const float*)d_in[5];
    const float* w2_0  = (const float*)d_in[6];
    const float* b2_0  = (const float*)d_in[7];
    const float* lng0  = (const float*)d_in[8];
    const float* lnb0  = (const float*)d_in[9];
    const float* w1_1  = (const float*)d_in[10];
    const float* b1_1  = (const float*)d_in[11];
    const float* w2_1  = (const float*)d_in[12];
    const float* b2_1  = (const float*)d_in[13];
    const float* lng1  = (const float*)d_in[14];
    const float* lnb1  = (const float*)d_in[15];
    const float* gw1   = (const float*)d_in[16];
    const float* gb1   = (const float*)d_in[17];
    const float* gw2   = (const float*)d_in[18];
    const float* gb2   = (const float*)d_in[19];
    const float* cw1   = (const float*)d_in[20];
    const float* cb1   = (const float*)d_in[21];
    const float* cw2   = (const float*)d_in[22];
    const float* cb2   = (const float*)d_in[23];

    int N = in_sizes[2];
    int E = in_sizes[1] / 2;
    int G = out_size / 2;
    const int* src = ei;
    const int* dst = ei + E;

    char* p = (char*)d_ws;
    auto alloc = [&](size_t bytes) {
        char* r = p;
        p += (bytes + 255) & ~(size_t)255;
        return r;
    };
    int*    row    = (int*)alloc((size_t)(N + 1) * 4);
    int*    cursor = (int*)alloc((size_t)N * 4);
    int*    srcl   = (int*)alloc((size_t)E * 4);
    float*  gate   = (float*)alloc((size_t)N * 4);
    float*  ebuf   = (float*)alloc((size_t)N * 4);
    int*    gstart = (int*)alloc((size_t)G * 4);
    int*    gend   = (int*)alloc((size_t)G * 4);
    ushort* xb     = (ushort*)alloc((size_t)N * 128 * 2);
    ushort* hsum0  = (ushort*)alloc((size_t)N * 128 * 2);
    ushort* h1     = (ushort*)alloc((size_t)N * 256 * 2);
    ushort* hsum1  = (ushort*)alloc((size_t)N * 256 * 2);
    ushort* h2     = (ushort*)alloc((size_t)N * 256 * 2);
    ushort* w1t0   = (ushort*)alloc(128 * 256 * 2);
    ushort* w2t0   = (ushort*)alloc(256 * 256 * 2);
    ushort* w1t1   = (ushort*)alloc(256 * 256 * 2);
    ushort* w2t1   = (ushort*)alloc(256 * 256 * 2);
    ushort* gw1t   = (ushort*)alloc(128 * 256 * 2);

    // weight prep, x cast, CSR build
    prep_weights<<<1024, 256, 0, stream>>>(w1_0, w2_0, w1_1, w2_1, gw1,
                                           w1t0, w2t0, w1t1, w2t1, gw1t);
    xcast<<<(N * 32 + 255) / 256, 256, 0, stream>>>(x, (unsigned long long*)xb, N * 32);
    hipMemsetAsync(cursor, 0, (size_t)N * 4, stream);
    count_deg<<<(E + 255) / 256, 256, 0, stream>>>(dst, cursor, E);
    scan_exclusive<<<1, 1024, 0, stream>>>(cursor, row, N);
    hipMemsetAsync(cursor, 0, (size_t)N * 4, stream);
    fill_csr<<<(E + 255) / 256, 256, 0, stream>>>(src, dst, row, cursor, srcl, E);

    int agg_blocks = (N + 3) / 4;
    int mlp_blocks = (N + 15) / 16;
    // layer 0
    aggregate0<<<agg_blocks, 256, 0, stream>>>((const unsigned*)xb, row, srcl,
                                               (unsigned*)hsum0, N);
    mlp_mfma<128, false><<<mlp_blocks, 64, 0, stream>>>(
        hsum0, w1t0, b1_0, w2t0, b2_0, lng0, lnb0, h1,
        nullptr, nullptr, nullptr, nullptr, nullptr, N);
    // layer 1 + fused gate
    aggregate1<<<agg_blocks, 256, 0, stream>>>((const unsigned long long*)h1, row, srcl,
                                               (unsigned long long*)hsum1, N);
    mlp_mfma<256, true><<<mlp_blocks, 64, 0, stream>>>(
        hsum1, w1t1, b1_1, w2t1, b2_1, lng1, lnb1, h2,
        gw1t, gb1, gw2, gb2, gate, N);
    // pooling + classifier
    hipMemsetAsync(gstart, 0, (size_t)G * 4, stream);
    hipMemsetAsync(gend, 0, (size_t)G * 4, stream);
    boundaries<<<(N + 255) / 256, 256, 0, stream>>>(batch, gstart, gend, N);
    pool_cls<<<G, 256, 0, stream>>>(h2, gate, gstart, gend, ebuf,
                                    cw1, cb1, cw2, cb2, (float*)d_out);
}

// Round 4
// 886.720 us; speedup vs baseline: 2.9674x; 1.4552x over previous
//
#include <hip/hip_runtime.h>
#include <math.h>

#define H 256

typedef short short8 __attribute__((ext_vector_type(8)));
typedef float f32x4 __attribute__((ext_vector_type(4)));

__device__ inline ushort f2bf(float f) {
    union { float f; unsigned u; } v; v.f = f;
    unsigned r = v.u + 0x7fff + ((v.u >> 16) & 1);
    return (ushort)(r >> 16);
}
__device__ inline float bf2f(unsigned h) {
    union { unsigned u; float f; } v; v.u = h << 16; return v.f;
}
__device__ inline unsigned pack2(float a, float b) {
    return (unsigned)f2bf(a) | ((unsigned)f2bf(b) << 16);
}

// ---------------- CSR build ----------------

__global__ void count_deg(const int* __restrict__ dst, int* __restrict__ deg, int E) {
    int e = blockIdx.x * blockDim.x + threadIdx.x;
    if (e < E) atomicAdd(&deg[dst[e]], 1);
}

__global__ void scan_exclusive(const int* __restrict__ deg, int* __restrict__ row, int n) {
    __shared__ int wsum[16];
    __shared__ int sh_carry;
    int tid = threadIdx.x;            // 1024 threads
    int lane = tid & 63, wid = tid >> 6;
    if (tid == 0) sh_carry = 0;
    __syncthreads();
    for (int base = 0; base < n; base += 1024) {
        int i = base + tid;
        int v = (i < n) ? deg[i] : 0;
        int x = v;
        #pragma unroll
        for (int off = 1; off < 64; off <<= 1) {
            int t = __shfl_up(x, off, 64);
            if (lane >= off) x += t;
        }
        if (lane == 63) wsum[wid] = x;
        __syncthreads();
        int carry = sh_carry;
        int wexc = 0;
        for (int w = 0; w < wid; ++w) wexc += wsum[w];
        int incl = carry + wexc + x;
        if (i < n) row[i + 1] = incl;
        __syncthreads();
        if (tid == 1023) sh_carry = incl;
    }
    __syncthreads();
    if (tid == 0) row[0] = 0;
}

__global__ void fill_csr(const int* __restrict__ src, const int* __restrict__ dst,
                         const int* __restrict__ row, int* __restrict__ cursor,
                         int* __restrict__ srcl, int E) {
    int e = blockIdx.x * blockDim.x + threadIdx.x;
    if (e < E) {
        int d = dst[e];
        int p = atomicAdd(&cursor[d], 1);
        srcl[row[d] + p] = src[e];
    }
}

// ---------------- weight prep: fp32 -> bf16 transposed ----------------

__global__ void prep_weights(const float* __restrict__ w10, const float* __restrict__ w20,
                             const float* __restrict__ w11, const float* __restrict__ w21,
                             const float* __restrict__ gw1,
                             ushort* __restrict__ w1t0, ushort* __restrict__ w2t0,
                             ushort* __restrict__ w1t1, ushort* __restrict__ w2t1,
                             ushort* __restrict__ gw1t) {
    int i = blockIdx.x * 256 + threadIdx.x;
    if (i < 32768) {                       // w10: 128x256
        int k = i >> 8, n = i & 255;
        w1t0[n * 128 + k] = f2bf(w10[i]);
    } else if (i < 32768 + 65536) {        // w20: 256x256
        int j = i - 32768; int k = j >> 8, n = j & 255;
        w2t0[n * 256 + k] = f2bf(w20[j]);
    } else if (i < 32768 + 131072) {       // w11: 256x256
        int j = i - (32768 + 65536); int k = j >> 8, n = j & 255;
        w1t1[n * 256 + k] = f2bf(w11[j]);
    } else if (i < 32768 + 196608) {       // w21: 256x256
        int j = i - (32768 + 131072); int k = j >> 8, n = j & 255;
        w2t1[n * 256 + k] = f2bf(w21[j]);
    } else if (i < 32768 + 196608 + 32768) { // gw1: 256x128
        int j = i - (32768 + 196608); int k = j >> 7, n = j & 127;
        gw1t[n * 256 + k] = f2bf(gw1[j]);
    }
}

// ---------------- x -> bf16 ----------------

__global__ void xcast(const float* __restrict__ x, unsigned long long* __restrict__ xb, int n4) {
    int i = blockIdx.x * 256 + threadIdx.x;
    if (i < n4) {
        f32x4 v = ((const f32x4*)x)[i];
        unsigned lo = pack2(v[0], v[1]);
        unsigned hi = pack2(v[2], v[3]);
        xb[i] = (unsigned long long)lo | ((unsigned long long)hi << 32);
    }
}

// ---------------- aggregation (wave per node) ----------------

__global__ void aggregate0(const unsigned* __restrict__ xb, const int* __restrict__ row,
                           const int* __restrict__ srcl, unsigned* __restrict__ out, int N) {
    int n = blockIdx.x * 4 + (threadIdx.x >> 6);
    int f = threadIdx.x & 63;
    if (n >= N) return;
    unsigned v = xb[(size_t)n * 64 + f];
    float a0 = bf2f(v & 0xffffu), a1 = bf2f(v >> 16);
    int s0 = row[n], s1 = row[n + 1];
    for (int e = s0; e < s1; ++e) {
        unsigned u = xb[(size_t)srcl[e] * 64 + f];
        a0 += bf2f(u & 0xffffu); a1 += bf2f(u >> 16);
    }
    out[(size_t)n * 64 + f] = pack2(a0, a1);
}

__global__ void aggregate1(const unsigned long long* __restrict__ h, const int* __restrict__ row,
                           const int* __restrict__ srcl, unsigned long long* __restrict__ out, int N) {
    int n = blockIdx.x * 4 + (threadIdx.x >> 6);
    int f = threadIdx.x & 63;
    if (n >= N) return;
    unsigned long long v = h[(size_t)n * 64 + f];
    float a0 = bf2f((unsigned)(v & 0xffff)), a1 = bf2f((unsigned)((v >> 16) & 0xffff));
    float a2 = bf2f((unsigned)((v >> 32) & 0xffff)), a3 = bf2f((unsigned)(v >> 48));
    int s0 = row[n], s1 = row[n + 1];
    for (int e = s0; e < s1; ++e) {
        unsigned long long u = h[(size_t)srcl[e] * 64 + f];
        a0 += bf2f((unsigned)(u & 0xffff));
        a1 += bf2f((unsigned)((u >> 16) & 0xffff));
        a2 += bf2f((unsigned)((u >> 32) & 0xffff));
        a3 += bf2f((unsigned)(u >> 48));
    }
    unsigned lo = pack2(a0, a1), hi = pack2(a2, a3);
    out[(size_t)n * 64 + f] = (unsigned long long)lo | ((unsigned long long)hi << 32);
}

// ---------------- fused MFMA MLP + LN (+ gate) ----------------
// 4 waves x 64 nodes/block. ft-split: wave w owns output-feature tiles
// {4w..4w+3} (GEMM1/GEMM2) resp {2w,2w+1} (gate). Each weight frag feeds
// 4 MFMAs (4 node tiles). hid staged in XOR-swizzled LDS.
// Swapped MFMA: C col = node (lane&15), C row = feat (4*(lane>>4)+r).

template<int K1, bool DO_GATE>
__global__ void __launch_bounds__(256, 3) mlp_mfma(
        const ushort* __restrict__ hsum, const ushort* __restrict__ w1t,
        const float* __restrict__ b1, const ushort* __restrict__ w2t,
        const float* __restrict__ b2, const float* __restrict__ lng,
        const float* __restrict__ lnb, ushort* __restrict__ hout,
        const ushort* __restrict__ gw1t, const float* __restrict__ gb1,
        const float* __restrict__ gw2, const float* __restrict__ gb2,
        float* __restrict__ gate, int N) {
    __shared__ ushort hid[64 * 256];       // 32KB, swizzled [node][feat]
    __shared__ float2 lnred[4 * 64];       // [wave][node]
    __shared__ float gred[4 * 64];
    int tid = threadIdx.x;
    int w = tid >> 6, lane = tid & 63;
    int ll = lane & 15, kg = lane >> 4;
    int n0 = blockIdx.x * 64;

    int nr[4];
    #pragma unroll
    for (int nt = 0; nt < 4; ++nt) {
        int n = n0 + 16 * nt + ll;
        nr[nt] = (n < N) ? n : N - 1;
    }

    // ---- GEMM1: hid^T tiles for wave's 4 feature-tiles x 4 node-tiles ----
    f32x4 acc[4][4];
    #pragma unroll
    for (int f = 0; f < 4; ++f)
        #pragma unroll
        for (int nt = 0; nt < 4; ++nt) acc[f][nt] = (f32x4){0.f, 0.f, 0.f, 0.f};
    #pragma unroll
    for (int kc = 0; kc < K1 / 32; ++kc) {
        short8 bfr[4];
        #pragma unroll
        for (int nt = 0; nt < 4; ++nt)
            bfr[nt] = *(const short8*)(hsum + (size_t)nr[nt] * K1 + kc * 32 + kg * 8);
        #pragma unroll
        for (int f = 0; f < 4; ++f) {
            short8 afr = *(const short8*)(w1t + (size_t)(16 * (4 * w + f) + ll) * K1 + kc * 32 + kg * 8);
            #pragma unroll
            for (int nt = 0; nt < 4; ++nt)
                acc[f][nt] = __builtin_amdgcn_mfma_f32_16x16x32_bf16(afr, bfr[nt], acc[f][nt], 0, 0, 0);
        }
    }
    // bias + relu + pack -> swizzled LDS
    #pragma unroll
    for (int f = 0; f < 4; ++f) {
        int feat0 = 16 * (4 * w + f) + 4 * kg;
        f32x4 bq = *(const f32x4*)(b1 + feat0);
        int fb = feat0 * 2;
        #pragma unroll
        for (int nt = 0; nt < 4; ++nt) {
            int node = 16 * nt + ll;
            float v0 = fmaxf(acc[f][nt][0] + bq[0], 0.f);
            float v1 = fmaxf(acc[f][nt][1] + bq[1], 0.f);
            float v2 = fmaxf(acc[f][nt][2] + bq[2], 0.f);
            float v3 = fmaxf(acc[f][nt][3] + bq[3], 0.f);
            unsigned lo = pack2(v0, v1), hi2 = pack2(v2, v3);
            int sb = node * 512 + ((((fb >> 4) ^ (node & 7))) << 4) + (fb & 15);
            *(unsigned long long*)((char*)hid + sb) =
                (unsigned long long)lo | ((unsigned long long)hi2 << 32);
        }
    }
    __syncthreads();

    // ---- GEMM2 ----
    #pragma unroll
    for (int f = 0; f < 4; ++f)
        #pragma unroll
        for (int nt = 0; nt < 4; ++nt) acc[f][nt] = (f32x4){0.f, 0.f, 0.f, 0.f};
    #pragma unroll
    for (int kc = 0; kc < 8; ++kc) {
        short8 bfr[4];
        int fb = kc * 64 + kg * 16;
        #pragma unroll
        for (int nt = 0; nt < 4; ++nt) {
            int node = 16 * nt + ll;
            int sb = node * 512 + ((((fb >> 4) ^ (node & 7))) << 4);
            bfr[nt] = *(const short8*)((char*)hid + sb);
        }
        #pragma unroll
        for (int f = 0; f < 4; ++f) {
            short8 afr = *(const short8*)(w2t + (size_t)(16 * (4 * w + f) + ll) * 256 + kc * 32 + kg * 8);
            #pragma unroll
            for (int nt = 0; nt < 4; ++nt)
                acc[f][nt] = __builtin_amdgcn_mfma_f32_16x16x32_bf16(afr, bfr[nt], acc[f][nt], 0, 0, 0);
        }
    }

    // ---- LayerNorm: per-node partial sums over this wave's 64 feats ----
    float sA[4] = {0, 0, 0, 0}, sB[4] = {0, 0, 0, 0};
    #pragma unroll
    for (int f = 0; f < 4; ++f) {
        int feat0 = 16 * (4 * w + f) + 4 * kg;
        f32x4 bq = *(const f32x4*)(b2 + feat0);
        #pragma unroll
        for (int nt = 0; nt < 4; ++nt) {
            #pragma unroll
            for (int r = 0; r < 4; ++r) {
                float v = acc[f][nt][r] + bq[r];
                acc[f][nt][r] = v;
                sA[nt] += v; sB[nt] += v * v;
            }
        }
    }
    #pragma unroll
    for (int nt = 0; nt < 4; ++nt) {
        sA[nt] += __shfl_xor(sA[nt], 16, 64); sA[nt] += __shfl_xor(sA[nt], 32, 64);
        sB[nt] += __shfl_xor(sB[nt], 16, 64); sB[nt] += __shfl_xor(sB[nt], 32, 64);
    }
    if (lane < 16) {
        #pragma unroll
        for (int nt = 0; nt < 4; ++nt)
            lnred[w * 64 + nt * 16 + ll] = make_float2(sA[nt], sB[nt]);
    }
    __syncthreads();   // lnred ready; also: all GEMM2 LDS reads done

    float mu[4], rs[4];
    #pragma unroll
    for (int nt = 0; nt < 4; ++nt) {
        float a = 0.f, b = 0.f;
        #pragma unroll
        for (int wv = 0; wv < 4; ++wv) {
            float2 t = lnred[wv * 64 + nt * 16 + ll];
            a += t.x; b += t.y;
        }
        float m = a * (1.f / 256.f);
        mu[nt] = m;
        rs[nt] = rsqrtf(b * (1.f / 256.f) - m * m + 1e-5f);
    }

    // ---- LN apply + relu: write h global (+ hid2 to LDS for gate) ----
    #pragma unroll
    for (int f = 0; f < 4; ++f) {
        int feat0 = 16 * (4 * w + f) + 4 * kg;
        f32x4 gq = *(const f32x4*)(lng + feat0);
        f32x4 bq = *(const f32x4*)(lnb + feat0);
        int fb = feat0 * 2;
        #pragma unroll
        for (int nt = 0; nt < 4; ++nt) {
            int node = 16 * nt + ll;
            int n = n0 + node;
            float v0 = fmaxf((acc[f][nt][0] - mu[nt]) * rs[nt] * gq[0] + bq[0], 0.f);
            float v1 = fmaxf((acc[f][nt][1] - mu[nt]) * rs[nt] * gq[1] + bq[1], 0.f);
            float v2 = fmaxf((acc[f][nt][2] - mu[nt]) * rs[nt] * gq[2] + bq[2], 0.f);
            float v3 = fmaxf((acc[f][nt][3] - mu[nt]) * rs[nt] * gq[3] + bq[3], 0.f);
            unsigned lo = pack2(v0, v1), hi2 = pack2(v2, v3);
            unsigned long long pv = (unsigned long long)lo | ((unsigned long long)hi2 << 32);
            if (n < N)
                *(unsigned long long*)(hout + (size_t)n * 256 + feat0) = pv;
            if (DO_GATE) {
                int sb = node * 512 + ((((fb >> 4) ^ (node & 7))) << 4) + (fb & 15);
                *(unsigned long long*)((char*)hid + sb) = pv;
            }
        }
    }

    // ---- gate MLP (ft-split: wave w owns gate-feat tiles 2w, 2w+1) ----
    if (DO_GATE) {
        __syncthreads();   // hid2 ready
        f32x4 ga[2][4];
        #pragma unroll
        for (int f = 0; f < 2; ++f)
            #pragma unroll
            for (int nt = 0; nt < 4; ++nt) ga[f][nt] = (f32x4){0.f, 0.f, 0.f, 0.f};
        #pragma unroll
        for (int kc = 0; kc < 8; ++kc) {
            short8 bfr[4];
            int fb = kc * 64 + kg * 16;
            #pragma unroll
            for (int nt = 0; nt < 4; ++nt) {
                int node = 16 * nt + ll;
                int sb = node * 512 + ((((fb >> 4) ^ (node & 7))) << 4);
                bfr[nt] = *(const short8*)((char*)hid + sb);
            }
            #pragma unroll
            for (int f = 0; f < 2; ++f) {
                short8 afr = *(const short8*)(gw1t + (size_t)(16 * (2 * w + f) + ll) * 256 + kc * 32 + kg * 8);
                #pragma unroll
                for (int nt = 0; nt < 4; ++nt)
                    ga[f][nt] = __builtin_amdgcn_mfma_f32_16x16x32_bf16(afr, bfr[nt], ga[f][nt], 0, 0, 0);
            }
        }
        float gp[4] = {0, 0, 0, 0};
        #pragma unroll
        for (int f = 0; f < 2; ++f) {
            int feat0 = 16 * (2 * w + f) + 4 * kg;
            f32x4 gbq = *(const f32x4*)(gb1 + feat0);
            f32x4 gwq = *(const f32x4*)(gw2 + feat0);
            #pragma unroll
            for (int nt = 0; nt < 4; ++nt)
                #pragma unroll
                for (int r = 0; r < 4; ++r)
                    gp[nt] += fmaxf(ga[f][nt][r] + gbq[r], 0.f) * gwq[r];
        }
        #pragma unroll
        for (int nt = 0; nt < 4; ++nt) {
            gp[nt] += __shfl_xor(gp[nt], 16, 64);
            gp[nt] += __shfl_xor(gp[nt], 32, 64);
        }
        if (lane < 16) {
            #pragma unroll
            for (int nt = 0; nt < 4; ++nt)
                gred[w * 64 + nt * 16 + ll] = gp[nt];
        }
        __syncthreads();
        if (w == 0 && lane < 16) {
            #pragma unroll
            for (int nt = 0; nt < 4; ++nt) {
                int n = n0 + 16 * nt + ll;
                if (n < N) {
                    float gs = gred[nt * 16 + ll] + gred[64 + nt * 16 + ll] +
                               gred[128 + nt * 16 + ll] + gred[192 + nt * 16 + ll];
                    gate[n] = gs + gb2[0];
                }
            }
        }
    }
}

// ---------------- graph ranges ----------------

__global__ void boundaries(const int* __restrict__ batch, int* __restrict__ gstart,
                           int* __restrict__ gend, int N) {
    int i = blockIdx.x * blockDim.x + threadIdx.x;
    if (i >= N) return;
    int b = batch[i];
    if (i == 0 || batch[i - 1] != b) gstart[b] = i;
    if (i == N - 1 || batch[i + 1] != b) gend[b] = i + 1;
}

// ---------------- per-graph softmax pooling + classifier ----------------

__global__ void pool_cls(const ushort* __restrict__ h, const float* __restrict__ gate,
                         const int* __restrict__ gstart, const int* __restrict__ gend,
                         float* __restrict__ ebuf,
                         const float* __restrict__ cw1, const float* __restrict__ cb1,
                         const float* __restrict__ cw2, const float* __restrict__ cb2,
                         float* __restrict__ out) {
    __shared__ float red[256];
    __shared__ float pool4[4 * 256];
    __shared__ float pooled[256];
    __shared__ float c2[128 * 2];
    int g = blockIdx.x;
    int tid = threadIdx.x;   // 256
    int s = gstart[g], e = gend[g];
    float lmax = -INFINITY;
    for (int n = s + tid; n < e; n += 256) lmax = fmaxf(lmax, gate[n]);
    red[tid] = lmax;
    __syncthreads();
    for (int off = 128; off > 0; off >>= 1) {
        if (tid < off) red[tid] = fmaxf(red[tid], red[tid + off]);
        __syncthreads();
    }
    float gmax = red[0];
    __syncthreads();
    float lsum = 0.f;
    for (int n = s + tid; n < e; n += 256) {
        float ev = expf(gate[n] - gmax);
        ebuf[n] = ev;
        lsum += ev;
    }
    red[tid] = lsum;
    __syncthreads();
    for (int off = 128; off > 0; off >>= 1) {
        if (tid < off) red[tid] += red[tid + off];
        __syncthreads();
    }
    float den = red[0];
    __syncthreads();
    // weighted pool: 4 node-groups x 64 feature-quads, u64 loads
    int ng = tid >> 6, fq = tid & 63;
    f32x4 a4 = {0.f, 0.f, 0.f, 0.f};
    for (int n = s + ng; n < e; n += 4) {
        float wv = ebuf[n];
        unsigned long long u = *(const unsigned long long*)(h + (size_t)n * 256 + fq * 4);
        a4[0] += bf2f((unsigned)(u & 0xffff)) * wv;
        a4[1] += bf2f((unsigned)((u >> 16) & 0xffff)) * wv;
        a4[2] += bf2f((unsigned)((u >> 32) & 0xffff)) * wv;
        a4[3] += bf2f((unsigned)(u >> 48)) * wv;
    }
    *(f32x4*)(pool4 + ng * 256 + fq * 4) = a4;
    __syncthreads();
    float pv = pool4[tid] + pool4[256 + tid] + pool4[512 + tid] + pool4[768 + tid];
    pooled[tid] = (e > s) ? pv / den : 0.f;
    __syncthreads();
    if (tid < 128) {
        int p = tid;
        float a = cb1[p];
        #pragma unroll 2
        for (int k = 0; k < H; ++k) a = fmaf(pooled[k], cw1[(size_t)k * 128 + p], a);
        a = fmaxf(a, 0.f);
        c2[p * 2 + 0] = a * cw2[p * 2 + 0];
        c2[p * 2 + 1] = a * cw2[p * 2 + 1];
    }
    __syncthreads();
    if (tid < 2) {
        float sres = cb2[tid];
        for (int p = 0; p < 128; ++p) sres += c2[p * 2 + tid];
        out[g * 2 + tid] = sres;
    }
}

// ---------------- launch ----------------

extern "C" void kernel_launch(void* const* d_in, const int* in_sizes, int n_in,
                              void* d_out, int out_size, void* d_ws, size_t ws_size,
                              hipStream_t stream) {
    const float* x     = (const float*)d_in[0];
    const int*   ei    = (const int*)d_in[1];
    const int*   batch = (const int*)d_in[2];
    const float* w1_0  = (const float*)d_in[4];
    const float* b1_0  = (const float*)d_in[5];
    const float* w2_0  = (const float*)d_in[6];
    const float* b2_0  = (const float*)d_in[7];
    const float* lng0  = (const float*)d_in[8];
    const float* lnb0  = (const float*)d_in[9];
    const float* w1_1  = (const float*)d_in[10];
    const float* b1_1  = (const float*)d_in[11];
    const float* w2_1  = (const float*)d_in[12];
    const float* b2_1  = (const float*)d_in[13];
    const float* lng1  = (const float*)d_in[14];
    const float* lnb1  = (const float*)d_in[15];
    const float* gw1   = (const float*)d_in[16];
    const float* gb1   = (const float*)d_in[17];
    const float* gw2   = (const float*)d_in[18];
    const float* gb2   = (const float*)d_in[19];
    const float* cw1   = (const float*)d_in[20];
    const float* cb1   = (const float*)d_in[21];
    const float* cw2   = (const float*)d_in[22];
    const float* cb2   = (const float*)d_in[23];

    int N = in_sizes[2];
    int E = in_sizes[1] / 2;
    int G = out_size / 2;
    const int* src = ei;
    const int* dst = ei + E;

    char* p = (char*)d_ws;
    auto alloc = [&](size_t bytes) {
        char* r = p;
        p += (bytes + 255) & ~(size_t)255;
        return r;
    };
    int*    row    = (int*)alloc((size_t)(N + 1) * 4);
    int*    cursor = (int*)alloc((size_t)N * 4);
    int*    srcl   = (int*)alloc((size_t)E * 4);
    float*  gate   = (float*)alloc((size_t)N * 4);
    float*  ebuf   = (float*)alloc((size_t)N * 4);
    int*    gstart = (int*)alloc((size_t)G * 4);
    int*    gend   = (int*)alloc((size_t)G * 4);
    ushort* xb     = (ushort*)alloc((size_t)N * 128 * 2);
    ushort* hsum0  = (ushort*)alloc((size_t)N * 128 * 2);
    ushort* h1     = (ushort*)alloc((size_t)N * 256 * 2);
    ushort* hsum1  = (ushort*)alloc((size_t)N * 256 * 2);
    ushort* h2     = (ushort*)alloc((size_t)N * 256 * 2);
    ushort* w1t0   = (ushort*)alloc(128 * 256 * 2);
    ushort* w2t0   = (ushort*)alloc(256 * 256 * 2);
    ushort* w1t1   = (ushort*)alloc(256 * 256 * 2);
    ushort* w2t1   = (ushort*)alloc(256 * 256 * 2);
    ushort* gw1t   = (ushort*)alloc(128 * 256 * 2);

    // weight prep, x cast, CSR build
    prep_weights<<<1024, 256, 0, stream>>>(w1_0, w2_0, w1_1, w2_1, gw1,
                                           w1t0, w2t0, w1t1, w2t1, gw1t);
    xcast<<<(N * 32 + 255) / 256, 256, 0, stream>>>(x, (unsigned long long*)xb, N * 32);
    hipMemsetAsync(cursor, 0, (size_t)N * 4, stream);
    count_deg<<<(E + 255) / 256, 256, 0, stream>>>(dst, cursor, E);
    scan_exclusive<<<1, 1024, 0, stream>>>(cursor, row, N);
    hipMemsetAsync(cursor, 0, (size_t)N * 4, stream);
    fill_csr<<<(E + 255) / 256, 256, 0, stream>>>(src, dst, row, cursor, srcl, E);

    int agg_blocks = (N + 3) / 4;
    int mlp_blocks = (N + 63) / 64;
    // layer 0
    aggregate0<<<agg_blocks, 256, 0, stream>>>((const unsigned*)xb, row, srcl,
                                               (unsigned*)hsum0, N);
    mlp_mfma<128, false><<<mlp_blocks, 256, 0, stream>>>(
        hsum0, w1t0, b1_0, w2t0, b2_0, lng0, lnb0, h1,
        nullptr, nullptr, nullptr, nullptr, nullptr, N);
    // layer 1 + fused gate
    aggregate1<<<agg_blocks, 256, 0, stream>>>((const unsigned long long*)h1, row, srcl,
                                               (unsigned long long*)hsum1, N);
    mlp_mfma<256, true><<<mlp_blocks, 256, 0, stream>>>(
        hsum1, w1t1, b1_1, w2t1, b2_1, lng1, lnb1, h2,
        gw1t, gb1, gw2, gb2, gate, N);
    // pooling + classifier
    hipMemsetAsync(gstart, 0, (size_t)G * 4, stream);
    hipMemsetAsync(gend, 0, (size_t)G * 4, stream);
    boundaries<<<(N + 255) / 256, 256, 0, stream>>>(batch, gstart, gend, N);
    pool_cls<<<G, 256, 0, stream>>>(h2, gate, gstart, gend, ebuf,
                                    cw1, cb1, cw2, cb2, (float*)d_out);
}

// Round 5
// 718.430 us; speedup vs baseline: 3.6626x; 1.2342x over previous
//
#include <hip/hip_runtime.h>
#include <math.h>

#define H 256

typedef float f32x4 __attribute__((ext_vector_type(4)));
typedef _Float16 half8 __attribute__((ext_vector_type(8)));
typedef _Float16 half4 __attribute__((ext_vector_type(4)));
typedef _Float16 half2v __attribute__((ext_vector_type(2)));
typedef unsigned long long u64;

__device__ inline unsigned pkh(float a, float b) {
    auto t = __builtin_amdgcn_cvt_pkrtz(a, b);   // v_cvt_pkrtz_f16_f32, 1 op
    union { decltype(t) h; unsigned u; } v; v.h = t; return v.u;
}
__device__ inline ushort f2h(float f) {
    union { _Float16 h; ushort u; } v; v.h = (_Float16)f; return v.u;
}

// ---------------- CSR build ----------------

__global__ void count_deg(const int* __restrict__ dst, int* __restrict__ deg, int E) {
    int e = blockIdx.x * blockDim.x + threadIdx.x;
    if (e < E) atomicAdd(&deg[dst[e]], 1);
}

__global__ void scan_exclusive(const int* __restrict__ deg, int* __restrict__ row, int n) {
    __shared__ int wsum[16];
    __shared__ int sh_carry;
    int tid = threadIdx.x;            // 1024 threads
    int lane = tid & 63, wid = tid >> 6;
    if (tid == 0) sh_carry = 0;
    __syncthreads();
    for (int base = 0; base < n; base += 1024) {
        int i = base + tid;
        int v = (i < n) ? deg[i] : 0;
        int x = v;
        #pragma unroll
        for (int off = 1; off < 64; off <<= 1) {
            int t = __shfl_up(x, off, 64);
            if (lane >= off) x += t;
        }
        if (lane == 63) wsum[wid] = x;
        __syncthreads();
        int carry = sh_carry;
        int wexc = 0;
        for (int w = 0; w < wid; ++w) wexc += wsum[w];
        int incl = carry + wexc + x;
        if (i < n) row[i + 1] = incl;
        __syncthreads();
        if (tid == 1023) sh_carry = incl;
    }
    __syncthreads();
    if (tid == 0) row[0] = 0;
}

__global__ void fill_csr(const int* __restrict__ src, const int* __restrict__ dst,
                         const int* __restrict__ row, int* __restrict__ cursor,
                         int* __restrict__ srcl, int E) {
    int e = blockIdx.x * blockDim.x + threadIdx.x;
    if (e < E) {
        int d = dst[e];
        int p = atomicAdd(&cursor[d], 1);
        srcl[row[d] + p] = src[e];
    }
}

// ---------------- weight prep: fp32 -> fp16 transposed ----------------

__global__ void prep_weights(const float* __restrict__ w10, const float* __restrict__ w20,
                             const float* __restrict__ w11, const float* __restrict__ w21,
                             const float* __restrict__ gw1,
                             ushort* __restrict__ w1t0, ushort* __restrict__ w2t0,
                             ushort* __restrict__ w1t1, ushort* __restrict__ w2t1,
                             ushort* __restrict__ gw1t) {
    int i = blockIdx.x * 256 + threadIdx.x;
    if (i < 32768) {                       // w10: 128x256
        int k = i >> 8, n = i & 255;
        w1t0[n * 128 + k] = f2h(w10[i]);
    } else if (i < 32768 + 65536) {        // w20: 256x256
        int j = i - 32768; int k = j >> 8, n = j & 255;
        w2t0[n * 256 + k] = f2h(w20[j]);
    } else if (i < 32768 + 131072) {       // w11: 256x256
        int j = i - (32768 + 65536); int k = j >> 8, n = j & 255;
        w1t1[n * 256 + k] = f2h(w11[j]);
    } else if (i < 32768 + 196608) {       // w21: 256x256
        int j = i - (32768 + 131072); int k = j >> 8, n = j & 255;
        w2t1[n * 256 + k] = f2h(w21[j]);
    } else if (i < 32768 + 196608 + 32768) { // gw1: 256x128
        int j = i - (32768 + 196608); int k = j >> 7, n = j & 127;
        gw1t[n * 256 + k] = f2h(gw1[j]);
    }
}

// ---------------- x -> fp16 ----------------

__global__ void xcast(const float* __restrict__ x, u64* __restrict__ xb, int n4) {
    int i = blockIdx.x * 256 + threadIdx.x;
    if (i < n4) {
        f32x4 v = ((const f32x4*)x)[i];
        xb[i] = (u64)pkh(v[0], v[1]) | ((u64)pkh(v[2], v[3]) << 32);
    }
}

// ---------------- aggregation (wave per node, 4-deep MLP unroll) ----------------
// layer0: x fp16 [N][128]: lane reads u32 (2 feats)

__global__ void aggregate0(const unsigned* __restrict__ xb, const int* __restrict__ row,
                           const int* __restrict__ srcl, unsigned* __restrict__ out, int N) {
    int n = blockIdx.x * 4 + (threadIdx.x >> 6);
    int f = threadIdx.x & 63;
    if (n >= N) return;
    union U { unsigned u; half2v h; };
    int s0 = row[n], s1 = row[n + 1];
    U a0, a1, a2, a3;
    a0.u = xb[(size_t)n * 64 + f];
    a1.h = (half2v)0; a2.h = (half2v)0; a3.h = (half2v)0;
    for (int base = s0; base < s1; base += 64) {
        int cnt = s1 - base; if (cnt > 64) cnt = 64;
        int idx = srcl[base + (f < cnt ? f : 0)];
        int j = 0;
        for (; j + 3 < cnt; j += 4) {
            int sa = __builtin_amdgcn_readlane(idx, j);
            int sb = __builtin_amdgcn_readlane(idx, j + 1);
            int sc = __builtin_amdgcn_readlane(idx, j + 2);
            int sd = __builtin_amdgcn_readlane(idx, j + 3);
            U u0, u1, u2, u3;
            u0.u = xb[(size_t)sa * 64 + f];
            u1.u = xb[(size_t)sb * 64 + f];
            u2.u = xb[(size_t)sc * 64 + f];
            u3.u = xb[(size_t)sd * 64 + f];
            a0.h += u0.h; a1.h += u1.h; a2.h += u2.h; a3.h += u3.h;
        }
        for (; j < cnt; ++j) {
            int sa = __builtin_amdgcn_readlane(idx, j);
            U u0; u0.u = xb[(size_t)sa * 64 + f];
            a0.h += u0.h;
        }
    }
    U r; r.h = (a0.h + a1.h) + (a2.h + a3.h);
    out[(size_t)n * 64 + f] = r.u;
}

// layer1: h fp16 [N][256]: lane reads u64 (4 feats)

__global__ void aggregate1(const u64* __restrict__ h, const int* __restrict__ row,
                           const int* __restrict__ srcl, u64* __restrict__ out, int N) {
    int n = blockIdx.x * 4 + (threadIdx.x >> 6);
    int f = threadIdx.x & 63;
    if (n >= N) return;
    union U { u64 u; half4 h; };
    int s0 = row[n], s1 = row[n + 1];
    U a0, a1, a2, a3;
    a0.u = h[(size_t)n * 64 + f];
    a1.h = (half4)0; a2.h = (half4)0; a3.h = (half4)0;
    for (int base = s0; base < s1; base += 64) {
        int cnt = s1 - base; if (cnt > 64) cnt = 64;
        int idx = srcl[base + (f < cnt ? f : 0)];
        int j = 0;
        for (; j + 3 < cnt; j += 4) {
            int sa = __builtin_amdgcn_readlane(idx, j);
            int sb = __builtin_amdgcn_readlane(idx, j + 1);
            int sc = __builtin_amdgcn_readlane(idx, j + 2);
            int sd = __builtin_amdgcn_readlane(idx, j + 3);
            U u0, u1, u2, u3;
            u0.u = h[(size_t)sa * 64 + f];
            u1.u = h[(size_t)sb * 64 + f];
            u2.u = h[(size_t)sc * 64 + f];
            u3.u = h[(size_t)sd * 64 + f];
            a0.h += u0.h; a1.h += u1.h; a2.h += u2.h; a3.h += u3.h;
        }
        for (; j < cnt; ++j) {
            int sa = __builtin_amdgcn_readlane(idx, j);
            U u0; u0.u = h[(size_t)sa * 64 + f];
            a0.h += u0.h;
        }
    }
    U r; r.h = (a0.h + a1.h) + (a2.h + a3.h);
    out[(size_t)n * 64 + f] = r.u;
}

// ---------------- fused MFMA MLP + LN (+ gate) ----------------
// 4 waves x 64 nodes/block. ft-split: wave w owns output-feature tiles
// {4w..4w+3} (GEMM1/GEMM2) resp {2w,2w+1} (gate). Each weight frag feeds
// 4 MFMAs (4 node tiles). hid staged in XOR-swizzled LDS.
// Swapped MFMA: C col = node (lane&15), C row = feat (4*(lane>>4)+r).

template<int K1, bool DO_GATE>
__global__ void __launch_bounds__(256, 3) mlp_mfma(
        const ushort* __restrict__ hsum, const ushort* __restrict__ w1t,
        const float* __restrict__ b1, const ushort* __restrict__ w2t,
        const float* __restrict__ b2, const float* __restrict__ lng,
        const float* __restrict__ lnb, ushort* __restrict__ hout,
        const ushort* __restrict__ gw1t, const float* __restrict__ gb1,
        const float* __restrict__ gw2, const float* __restrict__ gb2,
        float* __restrict__ gate, int N) {
    __shared__ ushort hid[64 * 256];       // 32KB, swizzled [node][feat]
    __shared__ float2 lnred[4 * 64];       // [wave][node]
    __shared__ float gred[4 * 64];
    int tid = threadIdx.x;
    int w = tid >> 6, lane = tid & 63;
    int ll = lane & 15, kg = lane >> 4;
    int n0 = blockIdx.x * 64;

    int nr[4];
    #pragma unroll
    for (int nt = 0; nt < 4; ++nt) {
        int n = n0 + 16 * nt + ll;
        nr[nt] = (n < N) ? n : N - 1;
    }

    // ---- GEMM1: hid^T tiles for wave's 4 feature-tiles x 4 node-tiles ----
    f32x4 acc[4][4];
    #pragma unroll
    for (int f = 0; f < 4; ++f)
        #pragma unroll
        for (int nt = 0; nt < 4; ++nt) acc[f][nt] = (f32x4){0.f, 0.f, 0.f, 0.f};
    #pragma unroll
    for (int kc = 0; kc < K1 / 32; ++kc) {
        half8 bfr[4];
        #pragma unroll
        for (int nt = 0; nt < 4; ++nt)
            bfr[nt] = *(const half8*)(hsum + (size_t)nr[nt] * K1 + kc * 32 + kg * 8);
        #pragma unroll
        for (int f = 0; f < 4; ++f) {
            half8 afr = *(const half8*)(w1t + (size_t)(16 * (4 * w + f) + ll) * K1 + kc * 32 + kg * 8);
            #pragma unroll
            for (int nt = 0; nt < 4; ++nt)
                acc[f][nt] = __builtin_amdgcn_mfma_f32_16x16x32_f16(afr, bfr[nt], acc[f][nt], 0, 0, 0);
        }
    }
    // bias + relu + pack -> swizzled LDS
    #pragma unroll
    for (int f = 0; f < 4; ++f) {
        int feat0 = 16 * (4 * w + f) + 4 * kg;
        f32x4 bq = *(const f32x4*)(b1 + feat0);
        int fb = feat0 * 2;
        #pragma unroll
        for (int nt = 0; nt < 4; ++nt) {
            int node = 16 * nt + ll;
            float v0 = fmaxf(acc[f][nt][0] + bq[0], 0.f);
            float v1 = fmaxf(acc[f][nt][1] + bq[1], 0.f);
            float v2 = fmaxf(acc[f][nt][2] + bq[2], 0.f);
            float v3 = fmaxf(acc[f][nt][3] + bq[3], 0.f);
            unsigned lo = pkh(v0, v1), hi2 = pkh(v2, v3);
            int sb = node * 512 + ((((fb >> 4) ^ (node & 7))) << 4) + (fb & 15);
            *(u64*)((char*)hid + sb) = (u64)lo | ((u64)hi2 << 32);
        }
    }
    __syncthreads();

    // ---- GEMM2 ----
    #pragma unroll
    for (int f = 0; f < 4; ++f)
        #pragma unroll
        for (int nt = 0; nt < 4; ++nt) acc[f][nt] = (f32x4){0.f, 0.f, 0.f, 0.f};
    #pragma unroll
    for (int kc = 0; kc < 8; ++kc) {
        half8 bfr[4];
        int fb = kc * 64 + kg * 16;
        #pragma unroll
        for (int nt = 0; nt < 4; ++nt) {
            int node = 16 * nt + ll;
            int sb = node * 512 + ((((fb >> 4) ^ (node & 7))) << 4);
            bfr[nt] = *(const half8*)((char*)hid + sb);
        }
        #pragma unroll
        for (int f = 0; f < 4; ++f) {
            half8 afr = *(const half8*)(w2t + (size_t)(16 * (4 * w + f) + ll) * 256 + kc * 32 + kg * 8);
            #pragma unroll
            for (int nt = 0; nt < 4; ++nt)
                acc[f][nt] = __builtin_amdgcn_mfma_f32_16x16x32_f16(afr, bfr[nt], acc[f][nt], 0, 0, 0);
        }
    }

    // ---- LayerNorm: per-node partial sums over this wave's 64 feats ----
    float sA[4] = {0, 0, 0, 0}, sB[4] = {0, 0, 0, 0};
    #pragma unroll
    for (int f = 0; f < 4; ++f) {
        int feat0 = 16 * (4 * w + f) + 4 * kg;
        f32x4 bq = *(const f32x4*)(b2 + feat0);
        #pragma unroll
        for (int nt = 0; nt < 4; ++nt) {
            #pragma unroll
            for (int r = 0; r < 4; ++r) {
                float v = acc[f][nt][r] + bq[r];
                acc[f][nt][r] = v;
                sA[nt] += v; sB[nt] += v * v;
            }
        }
    }
    #pragma unroll
    for (int nt = 0; nt < 4; ++nt) {
        sA[nt] += __shfl_xor(sA[nt], 16, 64); sA[nt] += __shfl_xor(sA[nt], 32, 64);
        sB[nt] += __shfl_xor(sB[nt], 16, 64); sB[nt] += __shfl_xor(sB[nt], 32, 64);
    }
    if (lane < 16) {
        #pragma unroll
        for (int nt = 0; nt < 4; ++nt)
            lnred[w * 64 + nt * 16 + ll] = make_float2(sA[nt], sB[nt]);
    }
    __syncthreads();   // lnred ready; also: all GEMM2 LDS reads done

    float mu[4], rs[4];
    #pragma unroll
    for (int nt = 0; nt < 4; ++nt) {
        float a = 0.f, b = 0.f;
        #pragma unroll
        for (int wv = 0; wv < 4; ++wv) {
            float2 t = lnred[wv * 64 + nt * 16 + ll];
            a += t.x; b += t.y;
        }
        float m = a * (1.f / 256.f);
        mu[nt] = m;
        rs[nt] = rsqrtf(b * (1.f / 256.f) - m * m + 1e-5f);
    }

    // ---- LN apply + relu: write h global (+ hid2 to LDS for gate) ----
    #pragma unroll
    for (int f = 0; f < 4; ++f) {
        int feat0 = 16 * (4 * w + f) + 4 * kg;
        f32x4 gq = *(const f32x4*)(lng + feat0);
        f32x4 bq = *(const f32x4*)(lnb + feat0);
        int fb = feat0 * 2;
        #pragma unroll
        for (int nt = 0; nt < 4; ++nt) {
            int node = 16 * nt + ll;
            int n = n0 + node;
            float v0 = fmaxf((acc[f][nt][0] - mu[nt]) * rs[nt] * gq[0] + bq[0], 0.f);
            float v1 = fmaxf((acc[f][nt][1] - mu[nt]) * rs[nt] * gq[1] + bq[1], 0.f);
            float v2 = fmaxf((acc[f][nt][2] - mu[nt]) * rs[nt] * gq[2] + bq[2], 0.f);
            float v3 = fmaxf((acc[f][nt][3] - mu[nt]) * rs[nt] * gq[3] + bq[3], 0.f);
            unsigned lo = pkh(v0, v1), hi2 = pkh(v2, v3);
            u64 pv = (u64)lo | ((u64)hi2 << 32);
            if (n < N)
                *(u64*)(hout + (size_t)n * 256 + feat0) = pv;
            if (DO_GATE) {
                int sb = node * 512 + ((((fb >> 4) ^ (node & 7))) << 4) + (fb & 15);
                *(u64*)((char*)hid + sb) = pv;
            }
        }
    }

    // ---- gate MLP (ft-split: wave w owns gate-feat tiles 2w, 2w+1) ----
    if (DO_GATE) {
        __syncthreads();   // hid2 ready
        f32x4 ga[2][4];
        #pragma unroll
        for (int f = 0; f < 2; ++f)
            #pragma unroll
            for (int nt = 0; nt < 4; ++nt) ga[f][nt] = (f32x4){0.f, 0.f, 0.f, 0.f};
        #pragma unroll
        for (int kc = 0; kc < 8; ++kc) {
            half8 bfr[4];
            int fb = kc * 64 + kg * 16;
            #pragma unroll
            for (int nt = 0; nt < 4; ++nt) {
                int node = 16 * nt + ll;
                int sb = node * 512 + ((((fb >> 4) ^ (node & 7))) << 4);
                bfr[nt] = *(const half8*)((char*)hid + sb);
            }
            #pragma unroll
            for (int f = 0; f < 2; ++f) {
                half8 afr = *(const half8*)(gw1t + (size_t)(16 * (2 * w + f) + ll) * 256 + kc * 32 + kg * 8);
                #pragma unroll
                for (int nt = 0; nt < 4; ++nt)
                    ga[f][nt] = __builtin_amdgcn_mfma_f32_16x16x32_f16(afr, bfr[nt], ga[f][nt], 0, 0, 0);
            }
        }
        float gp[4] = {0, 0, 0, 0};
        #pragma unroll
        for (int f = 0; f < 2; ++f) {
            int feat0 = 16 * (2 * w + f) + 4 * kg;
            f32x4 gbq = *(const f32x4*)(gb1 + feat0);
            f32x4 gwq = *(const f32x4*)(gw2 + feat0);
            #pragma unroll
            for (int nt = 0; nt < 4; ++nt)
                #pragma unroll
                for (int r = 0; r < 4; ++r)
                    gp[nt] += fmaxf(ga[f][nt][r] + gbq[r], 0.f) * gwq[r];
        }
        #pragma unroll
        for (int nt = 0; nt < 4; ++nt) {
            gp[nt] += __shfl_xor(gp[nt], 16, 64);
            gp[nt] += __shfl_xor(gp[nt], 32, 64);
        }
        if (lane < 16) {
            #pragma unroll
            for (int nt = 0; nt < 4; ++nt)
                gred[w * 64 + nt * 16 + ll] = gp[nt];
        }
        __syncthreads();
        if (w == 0 && lane < 16) {
            #pragma unroll
            for (int nt = 0; nt < 4; ++nt) {
                int n = n0 + 16 * nt + ll;
                if (n < N) {
                    float gs = gred[nt * 16 + ll] + gred[64 + nt * 16 + ll] +
                               gred[128 + nt * 16 + ll] + gred[192 + nt * 16 + ll];
                    gate[n] = gs + gb2[0];
                }
            }
        }
    }
}

// ---------------- graph ranges ----------------

__global__ void boundaries(const int* __restrict__ batch, int* __restrict__ gstart,
                           int* __restrict__ gend, int N) {
    int i = blockIdx.x * blockDim.x + threadIdx.x;
    if (i >= N) return;
    int b = batch[i];
    if (i == 0 || batch[i - 1] != b) gstart[b] = i;
    if (i == N - 1 || batch[i + 1] != b) gend[b] = i + 1;
}

// ---------------- per-graph softmax pooling + classifier ----------------

__global__ void pool_cls(const ushort* __restrict__ h, const float* __restrict__ gate,
                         const int* __restrict__ gstart, const int* __restrict__ gend,
                         float* __restrict__ ebuf,
                         const float* __restrict__ cw1, const float* __restrict__ cb1,
                         const float* __restrict__ cw2, const float* __restrict__ cb2,
                         float* __restrict__ out) {
    __shared__ float red[512];
    __shared__ float pool8[8 * 256];
    __shared__ float pooled[256];
    __shared__ float c2[128 * 2];
    int g = blockIdx.x;
    int tid = threadIdx.x;   // 512
    int s = gstart[g], e = gend[g];
    float lmax = -INFINITY;
    for (int n = s + tid; n < e; n += 512) lmax = fmaxf(lmax, gate[n]);
    red[tid] = lmax;
    __syncthreads();
    for (int off = 256; off > 0; off >>= 1) {
        if (tid < off) red[tid] = fmaxf(red[tid], red[tid + off]);
        __syncthreads();
    }
    float gmax = red[0];
    __syncthreads();
    float lsum = 0.f;
    for (int n = s + tid; n < e; n += 512) {
        float ev = expf(gate[n] - gmax);
        ebuf[n] = ev;
        lsum += ev;
    }
    red[tid] = lsum;
    __syncthreads();
    for (int off = 256; off > 0; off >>= 1) {
        if (tid < off) red[tid] += red[tid + off];
        __syncthreads();
    }
    float den = red[0];
    __syncthreads();
    // weighted pool: 8 node-groups x 64 feature-quads, u64 loads
    int ng = tid >> 6, fq = tid & 63;
    f32x4 a4 = {0.f, 0.f, 0.f, 0.f};
    for (int n = s + ng; n < e; n += 8) {
        float wv = ebuf[n];
        union { u64 u; half4 h; } v;
        v.u = *(const u64*)(h + (size_t)n * 256 + fq * 4);
        a4[0] += (float)v.h[0] * wv;
        a4[1] += (float)v.h[1] * wv;
        a4[2] += (float)v.h[2] * wv;
        a4[3] += (float)v.h[3] * wv;
    }
    *(f32x4*)(pool8 + ng * 256 + fq * 4) = a4;
    __syncthreads();
    if (tid < 256) {
        float pv = 0.f;
        #pragma unroll
        for (int q = 0; q < 8; ++q) pv += pool8[q * 256 + tid];
        pooled[tid] = (e > s) ? pv / den : 0.f;
    }
    __syncthreads();
    if (tid < 128) {
        int p = tid;
        float a = cb1[p];
        #pragma unroll 2
        for (int k = 0; k < H; ++k) a = fmaf(pooled[k], cw1[(size_t)k * 128 + p], a);
        a = fmaxf(a, 0.f);
        c2[p * 2 + 0] = a * cw2[p * 2 + 0];
        c2[p * 2 + 1] = a * cw2[p * 2 + 1];
    }
    __syncthreads();
    if (tid < 2) {
        float sres = cb2[tid];
        for (int p = 0; p < 128; ++p) sres += c2[p * 2 + tid];
        out[g * 2 + tid] = sres;
    }
}

// ---------------- launch ----------------

extern "C" void kernel_launch(void* const* d_in, const int* in_sizes, int n_in,
                              void* d_out, int out_size, void* d_ws, size_t ws_size,
                              hipStream_t stream) {
    const float* x     = (const float*)d_in[0];
    const int*   ei    = (const int*)d_in[1];
    const int*   batch = (const int*)d_in[2];
    const float* w1_0  = (const float*)d_in[4];
    const float* b1_0  = (const float*)d_in[5];
    const float* w2_0  = (const float*)d_in[6];
    const float* b2_0  = (const float*)d_in[7];
    const float* lng0  = (const float*)d_in[8];
    const float* lnb0  = (const float*)d_in[9];
    const float* w1_1  = (const float*)d_in[10];
    const float* b1_1  = (const float*)d_in[11];
    const float* w2_1  = (const float*)d_in[12];
    const float* b2_1  = (const float*)d_in[13];
    const float* lng1  = (const float*)d_in[14];
    const float* lnb1  = (const float*)d_in[15];
    const float* gw1   = (const float*)d_in[16];
    const float* gb1   = (const float*)d_in[17];
    const float* gw2   = (const float*)d_in[18];
    const float* gb2   = (const float*)d_in[19];
    const float* cw1   = (const float*)d_in[20];
    const float* cb1   = (const float*)d_in[21];
    const float* cw2   = (const float*)d_in[22];
    const float* cb2   = (const float*)d_in[23];

    int N = in_sizes[2];
    int E = in_sizes[1] / 2;
    int G = out_size / 2;
    const int* src = ei;
    const int* dst = ei + E;

    char* p = (char*)d_ws;
    auto alloc = [&](size_t bytes) {
        char* r = p;
        p += (bytes + 255) & ~(size_t)255;
        return r;
    };
    int*    row    = (int*)alloc((size_t)(N + 1) * 4);
    int*    cursor = (int*)alloc((size_t)N * 4);
    int*    srcl   = (int*)alloc((size_t)E * 4);
    float*  gate   = (float*)alloc((size_t)N * 4);
    float*  ebuf   = (float*)alloc((size_t)N * 4);
    int*    gstart = (int*)alloc((size_t)G * 4);
    int*    gend   = (int*)alloc((size_t)G * 4);
    ushort* xb     = (ushort*)alloc((size_t)N * 128 * 2);
    ushort* hsum0  = (ushort*)alloc((size_t)N * 128 * 2);
    ushort* h1     = (ushort*)alloc((size_t)N * 256 * 2);
    ushort* hsum1  = (ushort*)alloc((size_t)N * 256 * 2);
    ushort* h2     = (ushort*)alloc((size_t)N * 256 * 2);
    ushort* w1t0   = (ushort*)alloc(128 * 256 * 2);
    ushort* w2t0   = (ushort*)alloc(256 * 256 * 2);
    ushort* w1t1   = (ushort*)alloc(256 * 256 * 2);
    ushort* w2t1   = (ushort*)alloc(256 * 256 * 2);
    ushort* gw1t   = (ushort*)alloc(128 * 256 * 2);

    // weight prep, x cast, CSR build
    prep_weights<<<1024, 256, 0, stream>>>(w1_0, w2_0, w1_1, w2_1, gw1,
                                           w1t0, w2t0, w1t1, w2t1, gw1t);
    xcast<<<(N * 32 + 255) / 256, 256, 0, stream>>>(x, (u64*)xb, N * 32);
    hipMemsetAsync(cursor, 0, (size_t)N * 4, stream);
    count_deg<<<(E + 255) / 256, 256, 0, stream>>>(dst, cursor, E);
    scan_exclusive<<<1, 1024, 0, stream>>>(cursor, row, N);
    hipMemsetAsync(cursor, 0, (size_t)N * 4, stream);
    fill_csr<<<(E + 255) / 256, 256, 0, stream>>>(src, dst, row, cursor, srcl, E);

    int agg_blocks = (N + 3) / 4;
    int mlp_blocks = (N + 63) / 64;
    // layer 0
    aggregate0<<<agg_blocks, 256, 0, stream>>>((const unsigned*)xb, row, srcl,
                                               (unsigned*)hsum0, N);
    mlp_mfma<128, false><<<mlp_blocks, 256, 0, stream>>>(
        hsum0, w1t0, b1_0, w2t0, b2_0, lng0, lnb0, h1,
        nullptr, nullptr, nullptr, nullptr, nullptr, N);
    // layer 1 + fused gate
    aggregate1<<<agg_blocks, 256, 0, stream>>>((const u64*)h1, row, srcl,
                                               (u64*)hsum1, N);
    mlp_mfma<256, true><<<mlp_blocks, 256, 0, stream>>>(
        hsum1, w1t1, b1_1, w2t1, b2_1, lng1, lnb1, h2,
        gw1t, gb1, gw2, gb2, gate, N);
    // pooling + classifier
    hipMemsetAsync(gstart, 0, (size_t)G * 4, stream);
    hipMemsetAsync(gend, 0, (size_t)G * 4, stream);
    boundaries<<<(N + 255) / 256, 256, 0, stream>>>(batch, gstart, gend, N);
    pool_cls<<<G, 512, 0, stream>>>(h2, gate, gstart, gend, ebuf,
                                    cw1, cb1, cw2, cb2, (float*)d_out);
}

// Round 6
// 627.215 us; speedup vs baseline: 4.1952x; 1.1454x over previous
//
#include <hip/hip_runtime.h>
#include <math.h>

#define H 256

typedef float f32x4 __attribute__((ext_vector_type(4)));
typedef _Float16 half8 __attribute__((ext_vector_type(8)));
typedef _Float16 half4 __attribute__((ext_vector_type(4)));
typedef _Float16 half2v __attribute__((ext_vector_type(2)));
typedef unsigned long long u64;

__device__ inline unsigned pkh(float a, float b) {
    auto t = __builtin_amdgcn_cvt_pkrtz(a, b);
    union { decltype(t) h; unsigned u; } v; v.h = t; return v.u;
}
__device__ inline ushort f2h(float f) {
    union { _Float16 h; ushort u; } v; v.h = (_Float16)f; return v.u;
}

// ---------------- CSR build ----------------

__global__ void count_deg(const int* __restrict__ dst, int* __restrict__ deg, int E) {
    int e = blockIdx.x * blockDim.x + threadIdx.x;
    if (e < E) atomicAdd(&deg[dst[e]], 1);
}

// parallel 3-phase scan: per-block inclusive -> block-totals scan -> add offsets
__global__ void scan_block(const int* __restrict__ deg, int* __restrict__ row,
                           int* __restrict__ btot, int n) {
    __shared__ int wsum[16];
    int tid = threadIdx.x;            // 1024
    int lane = tid & 63, wid = tid >> 6;
    int i = blockIdx.x * 1024 + tid;
    int v = (i < n) ? deg[i] : 0;
    int x = v;
    #pragma unroll
    for (int off = 1; off < 64; off <<= 1) {
        int t = __shfl_up(x, off, 64);
        if (lane >= off) x += t;
    }
    if (lane == 63) wsum[wid] = x;
    __syncthreads();
    int wexc = 0;
    for (int w = 0; w < wid; ++w) wexc += wsum[w];
    int incl = wexc + x;
    if (i < n) row[i + 1] = incl;
    if (tid == 1023) btot[blockIdx.x] = incl;
}

__global__ void scan_tops(const int* __restrict__ btot, int* __restrict__ boff, int nb) {
    __shared__ int wsum[16];
    int tid = threadIdx.x;            // 1024
    int lane = tid & 63, wid = tid >> 6;
    int v = (tid < nb) ? btot[tid] : 0;
    int x = v;
    #pragma unroll
    for (int off = 1; off < 64; off <<= 1) {
        int t = __shfl_up(x, off, 64);
        if (lane >= off) x += t;
    }
    if (lane == 63) wsum[wid] = x;
    __syncthreads();
    int wexc = 0;
    for (int w = 0; w < wid; ++w) wexc += wsum[w];
    if (tid < nb) boff[tid] = wexc + x - v;   // exclusive
}

__global__ void scan_add(const int* __restrict__ boff, int* __restrict__ row, int n) {
    int i = blockIdx.x * 1024 + threadIdx.x;
    if (i == 0) row[0] = 0;
    if (i < n) row[i + 1] += boff[blockIdx.x];
}

__global__ void fill_csr(const int* __restrict__ src, const int* __restrict__ dst,
                         const int* __restrict__ row, int* __restrict__ cursor,
                         int* __restrict__ srcl, int E) {
    int e = blockIdx.x * blockDim.x + threadIdx.x;
    if (e < E) {
        int d = dst[e];
        int p = atomicAdd(&cursor[d], 1);
        srcl[row[d] + p] = src[e];
    }
}

// ---------------- weight prep: fp32 -> fp16 transposed ----------------

__global__ void prep_weights(const float* __restrict__ w10, const float* __restrict__ w20,
                             const float* __restrict__ w11, const float* __restrict__ w21,
                             const float* __restrict__ gw1,
                             ushort* __restrict__ w1t0, ushort* __restrict__ w2t0,
                             ushort* __restrict__ w1t1, ushort* __restrict__ w2t1,
                             ushort* __restrict__ gw1t) {
    int i = blockIdx.x * 256 + threadIdx.x;
    if (i < 32768) {                       // w10: 128x256
        int k = i >> 8, n = i & 255;
        w1t0[n * 128 + k] = f2h(w10[i]);
    } else if (i < 32768 + 65536) {        // w20: 256x256
        int j = i - 32768; int k = j >> 8, n = j & 255;
        w2t0[n * 256 + k] = f2h(w20[j]);
    } else if (i < 32768 + 131072) {       // w11: 256x256
        int j = i - (32768 + 65536); int k = j >> 8, n = j & 255;
        w1t1[n * 256 + k] = f2h(w11[j]);
    } else if (i < 32768 + 196608) {       // w21: 256x256
        int j = i - (32768 + 131072); int k = j >> 8, n = j & 255;
        w2t1[n * 256 + k] = f2h(w21[j]);
    } else if (i < 32768 + 196608 + 32768) { // gw1: 256x128
        int j = i - (32768 + 196608); int k = j >> 7, n = j & 127;
        gw1t[n * 256 + k] = f2h(gw1[j]);
    }
}

// ---------------- x -> fp16 ----------------

__global__ void xcast(const float* __restrict__ x, u64* __restrict__ xb, int n4) {
    int i = blockIdx.x * 256 + threadIdx.x;
    if (i < n4) {
        f32x4 v = ((const f32x4*)x)[i];
        xb[i] = (u64)pkh(v[0], v[1]) | ((u64)pkh(v[2], v[3]) << 32);
    }
}

// ---------------- aggregation (wave per node, 8-deep MLP unroll) ----------------

__global__ void aggregate0(const unsigned* __restrict__ xb, const int* __restrict__ row,
                           const int* __restrict__ srcl, unsigned* __restrict__ out, int N) {
    int n = blockIdx.x * 4 + (threadIdx.x >> 6);
    int f = threadIdx.x & 63;
    if (n >= N) return;
    union U { unsigned u; half2v h; };
    int s0 = row[n], s1 = row[n + 1];
    U a0, a1, a2, a3, a4, a5, a6, a7;
    a0.u = xb[(size_t)n * 64 + f];
    a1.h = (half2v)0; a2.h = (half2v)0; a3.h = (half2v)0;
    a4.h = (half2v)0; a5.h = (half2v)0; a6.h = (half2v)0; a7.h = (half2v)0;
    for (int base = s0; base < s1; base += 64) {
        int cnt = s1 - base; if (cnt > 64) cnt = 64;
        int idx = srcl[base + (f < cnt ? f : 0)];
        int j = 0;
        for (; j + 7 < cnt; j += 8) {
            U u0, u1, u2, u3, u4, u5, u6, u7;
            u0.u = xb[(size_t)__builtin_amdgcn_readlane(idx, j)     * 64 + f];
            u1.u = xb[(size_t)__builtin_amdgcn_readlane(idx, j + 1) * 64 + f];
            u2.u = xb[(size_t)__builtin_amdgcn_readlane(idx, j + 2) * 64 + f];
            u3.u = xb[(size_t)__builtin_amdgcn_readlane(idx, j + 3) * 64 + f];
            u4.u = xb[(size_t)__builtin_amdgcn_readlane(idx, j + 4) * 64 + f];
            u5.u = xb[(size_t)__builtin_amdgcn_readlane(idx, j + 5) * 64 + f];
            u6.u = xb[(size_t)__builtin_amdgcn_readlane(idx, j + 6) * 64 + f];
            u7.u = xb[(size_t)__builtin_amdgcn_readlane(idx, j + 7) * 64 + f];
            a0.h += u0.h; a1.h += u1.h; a2.h += u2.h; a3.h += u3.h;
            a4.h += u4.h; a5.h += u5.h; a6.h += u6.h; a7.h += u7.h;
        }
        for (; j + 3 < cnt; j += 4) {
            U u0, u1, u2, u3;
            u0.u = xb[(size_t)__builtin_amdgcn_readlane(idx, j)     * 64 + f];
            u1.u = xb[(size_t)__builtin_amdgcn_readlane(idx, j + 1) * 64 + f];
            u2.u = xb[(size_t)__builtin_amdgcn_readlane(idx, j + 2) * 64 + f];
            u3.u = xb[(size_t)__builtin_amdgcn_readlane(idx, j + 3) * 64 + f];
            a0.h += u0.h; a1.h += u1.h; a2.h += u2.h; a3.h += u3.h;
        }
        for (; j < cnt; ++j) {
            U u0; u0.u = xb[(size_t)__builtin_amdgcn_readlane(idx, j) * 64 + f];
            a0.h += u0.h;
        }
    }
    U r; r.h = ((a0.h + a1.h) + (a2.h + a3.h)) + ((a4.h + a5.h) + (a6.h + a7.h));
    out[(size_t)n * 64 + f] = r.u;
}

__global__ void aggregate1(const u64* __restrict__ h, const int* __restrict__ row,
                           const int* __restrict__ srcl, u64* __restrict__ out, int N) {
    int n = blockIdx.x * 4 + (threadIdx.x >> 6);
    int f = threadIdx.x & 63;
    if (n >= N) return;
    union U { u64 u; half4 h; };
    int s0 = row[n], s1 = row[n + 1];
    U a0, a1, a2, a3, a4, a5, a6, a7;
    a0.u = h[(size_t)n * 64 + f];
    a1.h = (half4)0; a2.h = (half4)0; a3.h = (half4)0;
    a4.h = (half4)0; a5.h = (half4)0; a6.h = (half4)0; a7.h = (half4)0;
    for (int base = s0; base < s1; base += 64) {
        int cnt = s1 - base; if (cnt > 64) cnt = 64;
        int idx = srcl[base + (f < cnt ? f : 0)];
        int j = 0;
        for (; j + 7 < cnt; j += 8) {
            U u0, u1, u2, u3, u4, u5, u6, u7;
            u0.u = h[(size_t)__builtin_amdgcn_readlane(idx, j)     * 64 + f];
            u1.u = h[(size_t)__builtin_amdgcn_readlane(idx, j + 1) * 64 + f];
            u2.u = h[(size_t)__builtin_amdgcn_readlane(idx, j + 2) * 64 + f];
            u3.u = h[(size_t)__builtin_amdgcn_readlane(idx, j + 3) * 64 + f];
            u4.u = h[(size_t)__builtin_amdgcn_readlane(idx, j + 4) * 64 + f];
            u5.u = h[(size_t)__builtin_amdgcn_readlane(idx, j + 5) * 64 + f];
            u6.u = h[(size_t)__builtin_amdgcn_readlane(idx, j + 6) * 64 + f];
            u7.u = h[(size_t)__builtin_amdgcn_readlane(idx, j + 7) * 64 + f];
            a0.h += u0.h; a1.h += u1.h; a2.h += u2.h; a3.h += u3.h;
            a4.h += u4.h; a5.h += u5.h; a6.h += u6.h; a7.h += u7.h;
        }
        for (; j + 3 < cnt; j += 4) {
            U u0, u1, u2, u3;
            u0.u = h[(size_t)__builtin_amdgcn_readlane(idx, j)     * 64 + f];
            u1.u = h[(size_t)__builtin_amdgcn_readlane(idx, j + 1) * 64 + f];
            u2.u = h[(size_t)__builtin_amdgcn_readlane(idx, j + 2) * 64 + f];
            u3.u = h[(size_t)__builtin_amdgcn_readlane(idx, j + 3) * 64 + f];
            a0.h += u0.h; a1.h += u1.h; a2.h += u2.h; a3.h += u3.h;
        }
        for (; j < cnt; ++j) {
            U u0; u0.u = h[(size_t)__builtin_amdgcn_readlane(idx, j) * 64 + f];
            a0.h += u0.h;
        }
    }
    U r; r.h = ((a0.h + a1.h) + (a2.h + a3.h)) + ((a4.h + a5.h) + (a6.h + a7.h));
    out[(size_t)n * 64 + f] = r.u;
}

// ---------------- fused MFMA MLP + LN (+ gate) ----------------
// 4 waves x 64 nodes/block; ft-split; explicit 1-ahead register prefetch in
// every kc loop so load latency overlaps the 16-MFMA batch.

template<int K1, bool DO_GATE>
__global__ void __launch_bounds__(256, 3) mlp_mfma(
        const ushort* __restrict__ hsum, const ushort* __restrict__ w1t,
        const float* __restrict__ b1, const ushort* __restrict__ w2t,
        const float* __restrict__ b2, const float* __restrict__ lng,
        const float* __restrict__ lnb, ushort* __restrict__ hout,
        const ushort* __restrict__ gw1t, const float* __restrict__ gb1,
        const float* __restrict__ gw2, const float* __restrict__ gb2,
        float* __restrict__ gate, int N) {
    __shared__ ushort hid[64 * 256];       // 32KB, swizzled [node][feat]
    __shared__ float2 lnred[4 * 64];       // [wave][node]
    __shared__ float gred[4 * 64];
    int tid = threadIdx.x;
    int w = tid >> 6, lane = tid & 63;
    int ll = lane & 15, kg = lane >> 4;
    int n0 = blockIdx.x * 64;

    int nr[4];
    #pragma unroll
    for (int nt = 0; nt < 4; ++nt) {
        int n = n0 + 16 * nt + ll;
        nr[nt] = (n < N) ? n : N - 1;
    }

    // ---- GEMM1 with 1-ahead prefetch ----
    constexpr int KC1 = K1 / 32;
    f32x4 acc[4][4];
    #pragma unroll
    for (int f = 0; f < 4; ++f)
        #pragma unroll
        for (int nt = 0; nt < 4; ++nt) acc[f][nt] = (f32x4){0.f, 0.f, 0.f, 0.f};
    {
        half8 bcur[4], wcur[4];
        #pragma unroll
        for (int nt = 0; nt < 4; ++nt)
            bcur[nt] = *(const half8*)(hsum + (size_t)nr[nt] * K1 + kg * 8);
        #pragma unroll
        for (int f = 0; f < 4; ++f)
            wcur[f] = *(const half8*)(w1t + (size_t)(16 * (4 * w + f) + ll) * K1 + kg * 8);
        #pragma unroll
        for (int kc = 0; kc < KC1; ++kc) {
            half8 bnx[4], wnx[4];
            if (kc + 1 < KC1) {
                #pragma unroll
                for (int nt = 0; nt < 4; ++nt)
                    bnx[nt] = *(const half8*)(hsum + (size_t)nr[nt] * K1 + (kc + 1) * 32 + kg * 8);
                #pragma unroll
                for (int f = 0; f < 4; ++f)
                    wnx[f] = *(const half8*)(w1t + (size_t)(16 * (4 * w + f) + ll) * K1 + (kc + 1) * 32 + kg * 8);
            }
            #pragma unroll
            for (int f = 0; f < 4; ++f)
                #pragma unroll
                for (int nt = 0; nt < 4; ++nt)
                    acc[f][nt] = __builtin_amdgcn_mfma_f32_16x16x32_f16(wcur[f], bcur[nt], acc[f][nt], 0, 0, 0);
            if (kc + 1 < KC1) {
                #pragma unroll
                for (int nt = 0; nt < 4; ++nt) bcur[nt] = bnx[nt];
                #pragma unroll
                for (int f = 0; f < 4; ++f) wcur[f] = wnx[f];
            }
        }
    }
    // bias + relu + pack -> swizzled LDS
    #pragma unroll
    for (int f = 0; f < 4; ++f) {
        int feat0 = 16 * (4 * w + f) + 4 * kg;
        f32x4 bq = *(const f32x4*)(b1 + feat0);
        int fb = feat0 * 2;
        #pragma unroll
        for (int nt = 0; nt < 4; ++nt) {
            int node = 16 * nt + ll;
            float v0 = fmaxf(acc[f][nt][0] + bq[0], 0.f);
            float v1 = fmaxf(acc[f][nt][1] + bq[1], 0.f);
            float v2 = fmaxf(acc[f][nt][2] + bq[2], 0.f);
            float v3 = fmaxf(acc[f][nt][3] + bq[3], 0.f);
            unsigned lo = pkh(v0, v1), hi2 = pkh(v2, v3);
            int sb = node * 512 + ((((fb >> 4) ^ (node & 7))) << 4) + (fb & 15);
            *(u64*)((char*)hid + sb) = (u64)lo | ((u64)hi2 << 32);
        }
    }
    __syncthreads();

    // ---- GEMM2 with 1-ahead weight prefetch (LDS reads stay inline) ----
    #pragma unroll
    for (int f = 0; f < 4; ++f)
        #pragma unroll
        for (int nt = 0; nt < 4; ++nt) acc[f][nt] = (f32x4){0.f, 0.f, 0.f, 0.f};
    {
        half8 wcur[4];
        #pragma unroll
        for (int f = 0; f < 4; ++f)
            wcur[f] = *(const half8*)(w2t + (size_t)(16 * (4 * w + f) + ll) * 256 + kg * 8);
        #pragma unroll
        for (int kc = 0; kc < 8; ++kc) {
            half8 wnx[4];
            if (kc < 7) {
                #pragma unroll
                for (int f = 0; f < 4; ++f)
                    wnx[f] = *(const half8*)(w2t + (size_t)(16 * (4 * w + f) + ll) * 256 + (kc + 1) * 32 + kg * 8);
            }
            half8 bfr[4];
            int fb = kc * 64 + kg * 16;
            #pragma unroll
            for (int nt = 0; nt < 4; ++nt) {
                int node = 16 * nt + ll;
                int sb = node * 512 + ((((fb >> 4) ^ (node & 7))) << 4);
                bfr[nt] = *(const half8*)((char*)hid + sb);
            }
            #pragma unroll
            for (int f = 0; f < 4; ++f)
                #pragma unroll
                for (int nt = 0; nt < 4; ++nt)
                    acc[f][nt] = __builtin_amdgcn_mfma_f32_16x16x32_f16(wcur[f], bfr[nt], acc[f][nt], 0, 0, 0);
            if (kc < 7) {
                #pragma unroll
                for (int f = 0; f < 4; ++f) wcur[f] = wnx[f];
            }
        }
    }

    // ---- LayerNorm ----
    float sA[4] = {0, 0, 0, 0}, sB[4] = {0, 0, 0, 0};
    #pragma unroll
    for (int f = 0; f < 4; ++f) {
        int feat0 = 16 * (4 * w + f) + 4 * kg;
        f32x4 bq = *(const f32x4*)(b2 + feat0);
        #pragma unroll
        for (int nt = 0; nt < 4; ++nt) {
            #pragma unroll
            for (int r = 0; r < 4; ++r) {
                float v = acc[f][nt][r] + bq[r];
                acc[f][nt][r] = v;
                sA[nt] += v; sB[nt] += v * v;
            }
        }
    }
    #pragma unroll
    for (int nt = 0; nt < 4; ++nt) {
        sA[nt] += __shfl_xor(sA[nt], 16, 64); sA[nt] += __shfl_xor(sA[nt], 32, 64);
        sB[nt] += __shfl_xor(sB[nt], 16, 64); sB[nt] += __shfl_xor(sB[nt], 32, 64);
    }
    if (lane < 16) {
        #pragma unroll
        for (int nt = 0; nt < 4; ++nt)
            lnred[w * 64 + nt * 16 + ll] = make_float2(sA[nt], sB[nt]);
    }
    __syncthreads();

    float mu[4], rs[4];
    #pragma unroll
    for (int nt = 0; nt < 4; ++nt) {
        float a = 0.f, b = 0.f;
        #pragma unroll
        for (int wv = 0; wv < 4; ++wv) {
            float2 t = lnred[wv * 64 + nt * 16 + ll];
            a += t.x; b += t.y;
        }
        float m = a * (1.f / 256.f);
        mu[nt] = m;
        rs[nt] = rsqrtf(b * (1.f / 256.f) - m * m + 1e-5f);
    }

    // ---- LN apply + relu: write h global (+ hid2 to LDS for gate) ----
    #pragma unroll
    for (int f = 0; f < 4; ++f) {
        int feat0 = 16 * (4 * w + f) + 4 * kg;
        f32x4 gq = *(const f32x4*)(lng + feat0);
        f32x4 bq = *(const f32x4*)(lnb + feat0);
        int fb = feat0 * 2;
        #pragma unroll
        for (int nt = 0; nt < 4; ++nt) {
            int node = 16 * nt + ll;
            int n = n0 + node;
            float v0 = fmaxf((acc[f][nt][0] - mu[nt]) * rs[nt] * gq[0] + bq[0], 0.f);
            float v1 = fmaxf((acc[f][nt][1] - mu[nt]) * rs[nt] * gq[1] + bq[1], 0.f);
            float v2 = fmaxf((acc[f][nt][2] - mu[nt]) * rs[nt] * gq[2] + bq[2], 0.f);
            float v3 = fmaxf((acc[f][nt][3] - mu[nt]) * rs[nt] * gq[3] + bq[3], 0.f);
            unsigned lo = pkh(v0, v1), hi2 = pkh(v2, v3);
            u64 pv = (u64)lo | ((u64)hi2 << 32);
            if (n < N)
                *(u64*)(hout + (size_t)n * 256 + feat0) = pv;
            if (DO_GATE) {
                int sb = node * 512 + ((((fb >> 4) ^ (node & 7))) << 4) + (fb & 15);
                *(u64*)((char*)hid + sb) = pv;
            }
        }
    }

    // ---- gate MLP with 1-ahead weight prefetch ----
    if (DO_GATE) {
        __syncthreads();
        f32x4 ga[2][4];
        #pragma unroll
        for (int f = 0; f < 2; ++f)
            #pragma unroll
            for (int nt = 0; nt < 4; ++nt) ga[f][nt] = (f32x4){0.f, 0.f, 0.f, 0.f};
        half8 wcur[2];
        #pragma unroll
        for (int f = 0; f < 2; ++f)
            wcur[f] = *(const half8*)(gw1t + (size_t)(16 * (2 * w + f) + ll) * 256 + kg * 8);
        #pragma unroll
        for (int kc = 0; kc < 8; ++kc) {
            half8 wnx[2];
            if (kc < 7) {
                #pragma unroll
                for (int f = 0; f < 2; ++f)
                    wnx[f] = *(const half8*)(gw1t + (size_t)(16 * (2 * w + f) + ll) * 256 + (kc + 1) * 32 + kg * 8);
            }
            half8 bfr[4];
            int fb = kc * 64 + kg * 16;
            #pragma unroll
            for (int nt = 0; nt < 4; ++nt) {
                int node = 16 * nt + ll;
                int sb = node * 512 + ((((fb >> 4) ^ (node & 7))) << 4);
                bfr[nt] = *(const half8*)((char*)hid + sb);
            }
            #pragma unroll
            for (int f = 0; f < 2; ++f)
                #pragma unroll
                for (int nt = 0; nt < 4; ++nt)
                    ga[f][nt] = __builtin_amdgcn_mfma_f32_16x16x32_f16(wcur[f], bfr[nt], ga[f][nt], 0, 0, 0);
            if (kc < 7) {
                #pragma unroll
                for (int f = 0; f < 2; ++f) wcur[f] = wnx[f];
            }
        }
        float gp[4] = {0, 0, 0, 0};
        #pragma unroll
        for (int f = 0; f < 2; ++f) {
            int feat0 = 16 * (2 * w + f) + 4 * kg;
            f32x4 gbq = *(const f32x4*)(gb1 + feat0);
            f32x4 gwq = *(const f32x4*)(gw2 + feat0);
            #pragma unroll
            for (int nt = 0; nt < 4; ++nt)
                #pragma unroll
                for (int r = 0; r < 4; ++r)
                    gp[nt] += fmaxf(ga[f][nt][r] + gbq[r], 0.f) * gwq[r];
        }
        #pragma unroll
        for (int nt = 0; nt < 4; ++nt) {
            gp[nt] += __shfl_xor(gp[nt], 16, 64);
            gp[nt] += __shfl_xor(gp[nt], 32, 64);
        }
        if (lane < 16) {
            #pragma unroll
            for (int nt = 0; nt < 4; ++nt)
                gred[w * 64 + nt * 16 + ll] = gp[nt];
        }
        __syncthreads();
        if (w == 0 && lane < 16) {
            #pragma unroll
            for (int nt = 0; nt < 4; ++nt) {
                int n = n0 + 16 * nt + ll;
                if (n < N) {
                    float gs = gred[nt * 16 + ll] + gred[64 + nt * 16 + ll] +
                               gred[128 + nt * 16 + ll] + gred[192 + nt * 16 + ll];
                    gate[n] = gs + gb2[0];
                }
            }
        }
    }
}

// ---------------- graph ranges ----------------

__global__ void boundaries(const int* __restrict__ batch, int* __restrict__ gstart,
                           int* __restrict__ gend, int N) {
    int i = blockIdx.x * blockDim.x + threadIdx.x;
    if (i >= N) return;
    int b = batch[i];
    if (i == 0 || batch[i - 1] != b) gstart[b] = i;
    if (i == N - 1 || batch[i + 1] != b) gend[b] = i + 1;
}

// ---------------- softmax pooling, split ----------------

__global__ void gate_stats(const float* __restrict__ gate, const int* __restrict__ gstart,
                           const int* __restrict__ gend, float* __restrict__ ebuf,
                           float* __restrict__ den) {
    __shared__ float red[256];
    int g = blockIdx.x;
    int tid = threadIdx.x;   // 256
    int s = gstart[g], e = gend[g];
    float lmax = -INFINITY;
    for (int n = s + tid; n < e; n += 256) lmax = fmaxf(lmax, gate[n]);
    red[tid] = lmax;
    __syncthreads();
    for (int off = 128; off > 0; off >>= 1) {
        if (tid < off) red[tid] = fmaxf(red[tid], red[tid + off]);
        __syncthreads();
    }
    float gmax = red[0];
    __syncthreads();
    float lsum = 0.f;
    for (int n = s + tid; n < e; n += 256) {
        float ev = expf(gate[n] - gmax);
        ebuf[n] = ev;
        lsum += ev;
    }
    red[tid] = lsum;
    __syncthreads();
    for (int off = 128; off > 0; off >>= 1) {
        if (tid < off) red[tid] += red[tid + off];
        __syncthreads();
    }
    if (tid == 0) den[g] = red[0];
}

// grid (G, 4): block handles 64 feats of one graph
__global__ void pool_feat(const ushort* __restrict__ h, const float* __restrict__ ebuf,
                          const float* __restrict__ den, const int* __restrict__ gstart,
                          const int* __restrict__ gend, float* __restrict__ pooled) {
    __shared__ float2 pl[256];
    int g = blockIdx.x, c = blockIdx.y;
    int tid = threadIdx.x;              // 256
    int fq = tid & 31, ng = tid >> 5;   // 32 feat-pairs x 8 node groups
    int s = gstart[g], e = gend[g];
    float2 acc = make_float2(0.f, 0.f);
    for (int n = s + ng; n < e; n += 8) {
        float wv = ebuf[n];
        union { unsigned u; half2v h2; } v;
        v.u = *(const unsigned*)(h + (size_t)n * 256 + c * 64 + fq * 2);
        acc.x += (float)v.h2[0] * wv;
        acc.y += (float)v.h2[1] * wv;
    }
    pl[tid] = acc;
    __syncthreads();
    if (tid < 32) {
        float2 a = pl[tid];
        #pragma unroll
        for (int q = 1; q < 8; ++q) {
            float2 t = pl[q * 32 + tid];
            a.x += t.x; a.y += t.y;
        }
        float d = (e > s) ? den[g] : 1.f;
        float inv = 1.f / d;
        pooled[g * 256 + c * 64 + fq * 2]     = (e > s) ? a.x * inv : 0.f;
        pooled[g * 256 + c * 64 + fq * 2 + 1] = (e > s) ? a.y * inv : 0.f;
    }
}

__global__ void cls_kernel(const float* __restrict__ pooled,
                           const float* __restrict__ cw1, const float* __restrict__ cb1,
                           const float* __restrict__ cw2, const float* __restrict__ cb2,
                           float* __restrict__ out) {
    __shared__ float pl[256];
    __shared__ float c2[256];
    int g = blockIdx.x;
    int tid = threadIdx.x;   // 128
    pl[tid] = pooled[g * 256 + tid];
    pl[tid + 128] = pooled[g * 256 + 128 + tid];
    __syncthreads();
    float a = cb1[tid];
    #pragma unroll 2
    for (int k = 0; k < H; ++k) a = fmaf(pl[k], cw1[(size_t)k * 128 + tid], a);
    a = fmaxf(a, 0.f);
    c2[tid * 2 + 0] = a * cw2[tid * 2 + 0];
    c2[tid * 2 + 1] = a * cw2[tid * 2 + 1];
    __syncthreads();
    if (tid < 2) {
        float sres = cb2[tid];
        for (int p = 0; p < 128; ++p) sres += c2[p * 2 + tid];
        out[g * 2 + tid] = sres;
    }
}

// ---------------- launch ----------------

extern "C" void kernel_launch(void* const* d_in, const int* in_sizes, int n_in,
                              void* d_out, int out_size, void* d_ws, size_t ws_size,
                              hipStream_t stream) {
    const float* x     = (const float*)d_in[0];
    const int*   ei    = (const int*)d_in[1];
    const int*   batch = (const int*)d_in[2];
    const float* w1_0  = (const float*)d_in[4];
    const float* b1_0  = (const float*)d_in[5];
    const float* w2_0  = (const float*)d_in[6];
    const float* b2_0  = (const float*)d_in[7];
    const float* lng0  = (const float*)d_in[8];
    const float* lnb0  = (const float*)d_in[9];
    const float* w1_1  = (const float*)d_in[10];
    const float* b1_1  = (const float*)d_in[11];
    const float* w2_1  = (const float*)d_in[12];
    const float* b2_1  = (const float*)d_in[13];
    const float* lng1  = (const float*)d_in[14];
    const float* lnb1  = (const float*)d_in[15];
    const float* gw1   = (const float*)d_in[16];
    const float* gb1   = (const float*)d_in[17];
    const float* gw2   = (const float*)d_in[18];
    const float* gb2   = (const float*)d_in[19];
    const float* cw1   = (const float*)d_in[20];
    const float* cb1   = (const float*)d_in[21];
    const float* cw2   = (const float*)d_in[22];
    const float* cb2   = (const float*)d_in[23];

    int N = in_sizes[2];
    int E = in_sizes[1] / 2;
    int G = out_size / 2;
    const int* src = ei;
    const int* dst = ei + E;

    char* p = (char*)d_ws;
    auto alloc = [&](size_t bytes) {
        char* r = p;
        p += (bytes + 255) & ~(size_t)255;
        return r;
    };
    int*    row    = (int*)alloc((size_t)(N + 1) * 4);
    int*    cursor = (int*)alloc((size_t)N * 4);
    int*    srcl   = (int*)alloc((size_t)E * 4);
    float*  gate   = (float*)alloc((size_t)N * 4);
    float*  ebuf   = (float*)alloc((size_t)N * 4);
    float*  den    = (float*)alloc((size_t)G * 4);
    float*  pooled = (float*)alloc((size_t)G * 256 * 4);
    int*    gstart = (int*)alloc((size_t)G * 4);
    int*    gend   = (int*)alloc((size_t)G * 4);
    int*    btot   = (int*)alloc(1024 * 4);
    int*    boff   = (int*)alloc(1024 * 4);
    ushort* xb     = (ushort*)alloc((size_t)N * 128 * 2);
    ushort* hsum0  = (ushort*)alloc((size_t)N * 128 * 2);
    ushort* h1     = (ushort*)alloc((size_t)N * 256 * 2);
    ushort* hsum1  = (ushort*)alloc((size_t)N * 256 * 2);
    ushort* h2     = (ushort*)alloc((size_t)N * 256 * 2);
    ushort* w1t0   = (ushort*)alloc(128 * 256 * 2);
    ushort* w2t0   = (ushort*)alloc(256 * 256 * 2);
    ushort* w1t1   = (ushort*)alloc(256 * 256 * 2);
    ushort* w2t1   = (ushort*)alloc(256 * 256 * 2);
    ushort* gw1t   = (ushort*)alloc(128 * 256 * 2);

    // weight prep, x cast, CSR build
    prep_weights<<<1024, 256, 0, stream>>>(w1_0, w2_0, w1_1, w2_1, gw1,
                                           w1t0, w2t0, w1t1, w2t1, gw1t);
    xcast<<<(N * 32 + 255) / 256, 256, 0, stream>>>(x, (u64*)xb, N * 32);
    hipMemsetAsync(cursor, 0, (size_t)N * 4, stream);
    count_deg<<<(E + 255) / 256, 256, 0, stream>>>(dst, cursor, E);
    int nb = (N + 1023) / 1024;
    scan_block<<<nb, 1024, 0, stream>>>(cursor, row, btot, N);
    scan_tops<<<1, 1024, 0, stream>>>(btot, boff, nb);
    scan_add<<<nb, 1024, 0, stream>>>(boff, row, N);
    hipMemsetAsync(cursor, 0, (size_t)N * 4, stream);
    fill_csr<<<(E + 255) / 256, 256, 0, stream>>>(src, dst, row, cursor, srcl, E);

    int agg_blocks = (N + 3) / 4;
    int mlp_blocks = (N + 63) / 64;
    // layer 0
    aggregate0<<<agg_blocks, 256, 0, stream>>>((const unsigned*)xb, row, srcl,
                                               (unsigned*)hsum0, N);
    mlp_mfma<128, false><<<mlp_blocks, 256, 0, stream>>>(
        hsum0, w1t0, b1_0, w2t0, b2_0, lng0, lnb0, h1,
        nullptr, nullptr, nullptr, nullptr, nullptr, N);
    // layer 1 + fused gate
    aggregate1<<<agg_blocks, 256, 0, stream>>>((const u64*)h1, row, srcl,
                                               (u64*)hsum1, N);
    mlp_mfma<256, true><<<mlp_blocks, 256, 0, stream>>>(
        hsum1, w1t1, b1_1, w2t1, b2_1, lng1, lnb1, h2,
        gw1t, gb1, gw2, gb2, gate, N);
    // pooling + classifier
    hipMemsetAsync(gstart, 0, (size_t)G * 4, stream);
    hipMemsetAsync(gend, 0, (size_t)G * 4, stream);
    boundaries<<<(N + 255) / 256, 256, 0, stream>>>(batch, gstart, gend, N);
    gate_stats<<<G, 256, 0, stream>>>(gate, gstart, gend, ebuf, den);
    pool_feat<<<dim3(G, 4), 256, 0, stream>>>(h2, ebuf, den, gstart, gend, pooled);
    cls_kernel<<<G, 128, 0, stream>>>(pooled, cw1, cb1, cw2, cb2, (float*)d_out);
}